// Round 1
// baseline (185.940 us; speedup 1.0000x reference)
//
#include <hip/hip_runtime.h>
#include <hip/hip_bf16.h>
#include <stdint.h>

typedef __attribute__((ext_vector_type(8))) short bf16x8;
typedef __attribute__((ext_vector_type(4))) float f32x4;

#define LN_EPS 1e-5f

// ---------------- helpers ----------------
__device__ inline unsigned short f2bf(float f) {
    unsigned u = __builtin_bit_cast(unsigned, f);
    u += 0x7fffu + ((u >> 16) & 1u);          // RNE
    return (unsigned short)(u >> 16);
}

__device__ inline float sigf(float x) {
    return 1.0f / (1.0f + __expf(-x));
}
__device__ inline float tanh_fast(float x) {
    // tanh(x) = 2*sigmoid(2x) - 1 ; exp overflow -> saturates correctly
    return __builtin_fmaf(2.0f, 1.0f / (1.0f + __expf(-2.0f * x)), -1.0f);
}

__device__ inline float wred(float v) {
#pragma unroll
    for (int o = 32; o > 0; o >>= 1) v += __shfl_xor(v, o);
    return v;
}

__device__ inline void gload_lds16(const void* g, void* l) {
    __builtin_amdgcn_global_load_lds(
        (const __attribute__((address_space(1))) void*)g,
        (__attribute__((address_space(3))) void*)l, 16, 0, 0);
}

// ---------------- cast f32 -> bf16 ----------------
__global__ __launch_bounds__(256) void cast_kernel(const float4* __restrict__ src,
                                                   ushort4* __restrict__ dst, int n4) {
    int i = blockIdx.x * blockDim.x + threadIdx.x;
    if (i < n4) {
        float4 v = src[i];
        ushort4 o;
        o.x = f2bf(v.x); o.y = f2bf(v.y); o.z = f2bf(v.z); o.w = f2bf(v.w);
        dst[i] = o;
    }
}

// ---------------- bf16 NT GEMM: C[M,N] = A[M,K] * B[N,K]^T ----------------
// 128x128 tile, BK=32, 4 waves (2x2 of 64x64), 16x16x32 MFMA. m97 structure.
#define BM 128
#define BN 128
#define BK 32

__global__ __launch_bounds__(256) void gemm_bt2(
    const short* __restrict__ A0, const short* __restrict__ B0, float* __restrict__ C0,
    const short* __restrict__ A1, const short* __restrict__ B1, float* __restrict__ C1,
    int M, int N, int K0, int K1)
{
    __shared__ __attribute__((aligned(16))) short As[BM * BK];
    __shared__ __attribute__((aligned(16))) short Bs[BN * BK];

    const short* __restrict__ A = blockIdx.z ? A1 : A0;
    const short* __restrict__ B = blockIdx.z ? B1 : B0;
    float* __restrict__ C       = blockIdx.z ? C1 : C0;
    const int K                 = blockIdx.z ? K1 : K0;

    const int t    = threadIdx.x;        // 0..255
    const int lane = t & 63;
    const int wave = t >> 6;

    const int brow = blockIdx.y * BM;
    const int bcol = blockIdx.x * BN;

    f32x4 acc[4][4];
#pragma unroll
    for (int i = 0; i < 4; ++i)
#pragma unroll
        for (int j = 0; j < 4; ++j)
            acc[i][j] = (f32x4){0.f, 0.f, 0.f, 0.f};

    const int lr = lane & 15;            // row within 16x16 fragment
    const int lk = (lane >> 4) * 8;      // k offset within fragment
    const int mrow = (wave >> 1) * 64;   // wave sub-tile
    const int ncol = (wave & 1) * 64;

    const int nk = K / BK;
    for (int kt = 0; kt < nk; ++kt) {
        const int k0 = kt * BK;
        // ---- stage A and B tiles: global -> LDS, 16B per lane ----
#pragma unroll
        for (int c = 0; c < 2; ++c) {
            const int e   = c * 256 + t;       // 16B-chunk index, 0..511
            const int row = e >> 2;            // 0..127
            const int ch  = e & 3;             // 16B chunk within 64B row
            const int ldsbase = (c * 256 + (t & 192)) * 8;  // wave-uniform (shorts)
            gload_lds16(A + (size_t)(brow + row) * K + k0 + ch * 8, &As[ldsbase]);
            gload_lds16(B + (size_t)(bcol + row) * K + k0 + ch * 8, &Bs[ldsbase]);
        }
        __syncthreads();   // compiler emits vmcnt(0) drain before barrier

        bf16x8 a[4], b[4];
#pragma unroll
        for (int i = 0; i < 4; ++i)
            a[i] = *reinterpret_cast<const bf16x8*>(&As[(mrow + i * 16 + lr) * BK + lk]);
#pragma unroll
        for (int j = 0; j < 4; ++j)
            b[j] = *reinterpret_cast<const bf16x8*>(&Bs[(ncol + j * 16 + lr) * BK + lk]);
#pragma unroll
        for (int i = 0; i < 4; ++i)
#pragma unroll
            for (int j = 0; j < 4; ++j)
                acc[i][j] = __builtin_amdgcn_mfma_f32_16x16x32_bf16(a[i], b[j], acc[i][j], 0, 0, 0);
        __syncthreads();
    }

    // ---- epilogue: C/D layout col=lane&15, row=(lane>>4)*4+r ----
    const int crow0 = brow + mrow + (lane >> 4) * 4;
    const int ccol0 = bcol + ncol + (lane & 15);
#pragma unroll
    for (int i = 0; i < 4; ++i)
#pragma unroll
        for (int j = 0; j < 4; ++j)
#pragma unroll
            for (int r = 0; r < 4; ++r)
                C[(size_t)(crow0 + i * 16 + r) * N + ccol0 + j * 16] = acc[i][j][r];
}

// ---------------- fused LN + LSTM pointwise ----------------
// one block (256 thr) per batch row
__global__ __launch_bounds__(256) void ln_lstm(
    const float* __restrict__ i2h,   // [B,4H]
    const float* __restrict__ h2h,   // [B,4H] (bias not yet added)
    const float* __restrict__ cx,    // [B,H]
    const float* __restrict__ b_hh,  // [4H]
    const float* __restrict__ g_ih, const float* __restrict__ be_ih,
    const float* __restrict__ g_hh, const float* __restrict__ be_hh,
    const float* __restrict__ g_ho, const float* __restrict__ be_ho,
    float* __restrict__ hy, float* __restrict__ cy, int H)
{
    const int b = blockIdx.x;
    const int t = threadIdx.x;
    const int lane = t & 63;
    const int wave = t >> 6;
    const int H4 = 4 * H;

    const float* xi = i2h + (size_t)b * H4;
    const float* xh = h2h + (size_t)b * H4;

    __shared__ float red[4][4];

    // ---- pass 1: stats over 4H for both LNs ----
    float si = 0.f, qi = 0.f, sh = 0.f, qh = 0.f;
    for (int j = t * 4; j < H4; j += 256 * 4) {
        float4 vi = *reinterpret_cast<const float4*>(xi + j);
        float4 vh = *reinterpret_cast<const float4*>(xh + j);
        float4 vb = *reinterpret_cast<const float4*>(b_hh + j);
        si += vi.x + vi.y + vi.z + vi.w;
        qi += vi.x * vi.x + vi.y * vi.y + vi.z * vi.z + vi.w * vi.w;
        float h0 = vh.x + vb.x, h1 = vh.y + vb.y, h2 = vh.z + vb.z, h3 = vh.w + vb.w;
        sh += h0 + h1 + h2 + h3;
        qh += h0 * h0 + h1 * h1 + h2 * h2 + h3 * h3;
    }
    si = wred(si); qi = wred(qi); sh = wred(sh); qh = wred(qh);
    if (lane == 0) { red[wave][0] = si; red[wave][1] = qi; red[wave][2] = sh; red[wave][3] = qh; }
    __syncthreads();
    float Si = red[0][0] + red[1][0] + red[2][0] + red[3][0];
    float Qi = red[0][1] + red[1][1] + red[2][1] + red[3][1];
    float Sh = red[0][2] + red[1][2] + red[2][2] + red[3][2];
    float Qh = red[0][3] + red[1][3] + red[2][3] + red[3][3];
    const float inv4H = 1.0f / (float)H4;
    float mi = Si * inv4H, mh = Sh * inv4H;
    float ri = rsqrtf(Qi * inv4H - mi * mi + LN_EPS);
    float rh = rsqrtf(Qh * inv4H - mh * mh + LN_EPS);

    // ---- pass 2: gates, cy, tanh(cy) ----
    float tv[4], ov[4];
    float s2 = 0.f, q2 = 0.f;
#pragma unroll
    for (int u = 0; u < 4; ++u) {
        const int h = t + u * 256;
        const int ji = h, jf = H + h, jo = 2 * H + h, jg = 3 * H + h;
        float gi = (xi[ji] - mi) * ri * g_ih[ji] + be_ih[ji]
                 + (xh[ji] + b_hh[ji] - mh) * rh * g_hh[ji] + be_hh[ji];
        float gf = (xi[jf] - mi) * ri * g_ih[jf] + be_ih[jf]
                 + (xh[jf] + b_hh[jf] - mh) * rh * g_hh[jf] + be_hh[jf];
        float go = (xi[jo] - mi) * ri * g_ih[jo] + be_ih[jo]
                 + (xh[jo] + b_hh[jo] - mh) * rh * g_hh[jo] + be_hh[jo];
        float gg = (xi[jg] - mi) * ri * g_ih[jg] + be_ih[jg]
                 + (xh[jg] + b_hh[jg] - mh) * rh * g_hh[jg] + be_hh[jg];
        float c = sigf(gf) * cx[(size_t)b * H + h] + sigf(gi) * tanh_fast(gg);
        cy[(size_t)b * H + h] = c;
        float tc = tanh_fast(c);
        tv[u] = tc; ov[u] = sigf(go);
        s2 += tc; q2 += tc * tc;
    }
    s2 = wred(s2); q2 = wred(q2);
    __syncthreads();     // red[] reuse
    if (lane == 0) { red[wave][0] = s2; red[wave][1] = q2; }
    __syncthreads();
    float S2 = red[0][0] + red[1][0] + red[2][0] + red[3][0];
    float Q2 = red[0][1] + red[1][1] + red[2][1] + red[3][1];
    const float invH = 1.0f / (float)H;
    float mt = S2 * invH;
    float rt = rsqrtf(Q2 * invH - mt * mt + LN_EPS);
#pragma unroll
    for (int u = 0; u < 4; ++u) {
        const int h = t + u * 256;
        hy[(size_t)b * H + h] = ov[u] * ((tv[u] - mt) * rt * g_ho[h] + be_ho[h]);
    }
}

// ---------------- launcher ----------------
extern "C" void kernel_launch(void* const* d_in, const int* in_sizes, int n_in,
                              void* d_out, int out_size, void* d_ws, size_t ws_size,
                              hipStream_t stream) {
    const float* inputs  = (const float*)d_in[0];
    const float* hx      = (const float*)d_in[1];
    const float* cx      = (const float*)d_in[2];
    const float* w_ih    = (const float*)d_in[3];
    const float* w_hh    = (const float*)d_in[4];
    const float* b_hh    = (const float*)d_in[5];
    const float* g_ih    = (const float*)d_in[6];
    const float* beta_ih = (const float*)d_in[7];
    const float* g_hh    = (const float*)d_in[8];
    const float* beta_hh = (const float*)d_in[9];
    const float* g_ho    = (const float*)d_in[10];
    const float* beta_ho = (const float*)d_in[11];

    const int H  = in_sizes[10];            // 1024
    const int B  = in_sizes[1] / H;         // 4096
    const int D  = in_sizes[0] / B;         // 1024
    const int H4 = 4 * H;

    uint8_t* ws = (uint8_t*)d_ws;
    size_t off = 0;
    short* Abf  = (short*)(ws + off); off += (size_t)B * D * 2;
    short* Hbf  = (short*)(ws + off); off += (size_t)B * H * 2;
    short* Wih  = (short*)(ws + off); off += (size_t)H4 * D * 2;
    short* Whh  = (short*)(ws + off); off += (size_t)H4 * H * 2;
    float* i2h  = (float*)(ws + off); off += (size_t)B * H4 * 4;
    float* h2h  = (float*)(ws + off); off += (size_t)B * H4 * 4;

    float* hy = (float*)d_out;
    float* cyo = (float*)d_out + (size_t)B * H;

    // 1) casts
    {
        int n4 = (B * D) / 4;
        cast_kernel<<<(n4 + 255) / 256, 256, 0, stream>>>((const float4*)inputs, (ushort4*)Abf, n4);
        n4 = (B * H) / 4;
        cast_kernel<<<(n4 + 255) / 256, 256, 0, stream>>>((const float4*)hx, (ushort4*)Hbf, n4);
        n4 = (H4 * D) / 4;
        cast_kernel<<<(n4 + 255) / 256, 256, 0, stream>>>((const float4*)w_ih, (ushort4*)Wih, n4);
        n4 = (H4 * H) / 4;
        cast_kernel<<<(n4 + 255) / 256, 256, 0, stream>>>((const float4*)w_hh, (ushort4*)Whh, n4);
    }

    // 2) both GEMMs in one launch (z selects)
    {
        dim3 grid(H4 / BN, B / BM, 2);
        gemm_bt2<<<grid, 256, 0, stream>>>(Abf, Wih, i2h, Hbf, Whh, h2h, B, H4, D, H);
    }

    // 3) fused LN + LSTM
    ln_lstm<<<B, 256, 0, stream>>>(i2h, h2h, cx, b_hh, g_ih, beta_ih, g_hh, beta_hh,
                                   g_ho, beta_ho, hy, cyo, H);
}

// Round 2
// 166.053 us; speedup vs baseline: 1.1198x; 1.1198x over previous
//
#include <hip/hip_runtime.h>
#include <hip/hip_bf16.h>
#include <stdint.h>

typedef __attribute__((ext_vector_type(8))) short bf16x8;
typedef __attribute__((ext_vector_type(4))) float f32x4;

#define LN_EPS 1e-5f

// ---------------- helpers ----------------
__device__ inline unsigned short f2bf(float f) {
    unsigned u = __builtin_bit_cast(unsigned, f);
    u += 0x7fffu + ((u >> 16) & 1u);          // RNE
    return (unsigned short)(u >> 16);
}

__device__ inline float sigf(float x) {
    return 1.0f / (1.0f + __expf(-x));
}
__device__ inline float tanh_fast(float x) {
    return __builtin_fmaf(2.0f, 1.0f / (1.0f + __expf(-2.0f * x)), -1.0f);
}

__device__ inline float wred(float v) {
#pragma unroll
    for (int o = 32; o > 0; o >>= 1) v += __shfl_xor(v, o);
    return v;
}

__device__ inline void gload_lds16(const void* g, void* l) {
    __builtin_amdgcn_global_load_lds(
        (const __attribute__((address_space(1))) void*)g,
        (__attribute__((address_space(3))) void*)l, 16, 0, 0);
}

// ---------------- cast f32 -> bf16 ----------------
__global__ __launch_bounds__(256) void cast_kernel(const float4* __restrict__ src,
                                                   ushort4* __restrict__ dst, int n4) {
    int i = blockIdx.x * blockDim.x + threadIdx.x;
    if (i < n4) {
        float4 v = src[i];
        ushort4 o;
        o.x = f2bf(v.x); o.y = f2bf(v.y); o.z = f2bf(v.z); o.w = f2bf(v.w);
        dst[i] = o;
    }
}

// =====================================================================
// 256x256 bf16 NT GEMM, 8-phase-style pipelined schedule.
// BK=32 K-tiles, ring-4 LDS slots/matrix (128 KiB), 2 phases per tile,
// counted vmcnt(6) (T4), setprio around MFMA (T5), XOR chunk swizzle (T2),
// bijective XCD blockIdx swizzle (T1).
//
// Granule order: A(0),B(0),A(1),B(1),A(2) [prologue], then phase p stages
// granule p+5 (phase 2T+0 -> B(T+2), phase 2T+1 -> A(T+3)).
// vmcnt(6) at end of each tile => tiles T+1's granules landed; in-flight
// granules only ever target slots (T+1)&3 / (T+2)&3 != (T)&3.
// =====================================================================
#define GNT 32   // K / 32 = 1024 / 32

__global__ __launch_bounds__(512) void gemm8p(
    const short* __restrict__ Aa, const short* __restrict__ Ba, float* __restrict__ Ca,
    const short* __restrict__ Ab, const short* __restrict__ Bb, float* __restrict__ Cb,
    int N, int K)
{
    __shared__ __attribute__((aligned(16))) short lds[65536];  // 128 KiB
    short* ldsA = lds;            // 4 slots x 8192 shorts (256 rows x 32 k)
    short* ldsB = lds + 32768;    // 4 slots x 8192 shorts

    // ---- T1: bijective XCD swizzle over 512 blocks ----
    const int gx  = gridDim.x;            // 16
    const int gxy = gx * gridDim.y;       // 256
    int bid = (blockIdx.z * gridDim.y + blockIdx.y) * gx + blockIdx.x;
    const int cpx = (gxy * gridDim.z) >> 3;   // 64
    int swz = (bid & 7) * cpx + (bid >> 3);
    const int z  = swz / gxy;
    const int r2 = swz - z * gxy;
    const int by = r2 / gx;
    const int bx = r2 - by * gx;

    const short* __restrict__ A = z ? Ab : Aa;
    const short* __restrict__ B = z ? Bb : Ba;
    float* __restrict__ C       = z ? Cb : Ca;
    const int brow = by * 256, bcol = bx * 256;

    const int t    = threadIdx.x;         // 0..511
    const int lane = t & 63, w = t >> 6;
    const int wr = w >> 2, wc = w & 3;    // 2x4 wave grid; wave tile 128x64
    const int lr = lane & 15, kc = lane >> 4;

    // ---- staging addresses: thread stages chunks t and t+512 (16B each) ----
    const int ci0 = t, ci1 = t + 512;
    const int r0 = ci0 >> 2, l0 = (ci0 & 3) ^ ((r0 >> 1) & 3);   // T2 pre-swizzled source
    const int r1 = ci1 >> 2, l1 = (ci1 & 3) ^ ((r1 >> 1) & 3);
    const int gA0 = (brow + r0) * K + l0 * 8;
    const int gA1 = (brow + r1) * K + l1 * 8;
    const int gB0 = (bcol + r0) * K + l0 * 8;
    const int gB1 = (bcol + r1) * K + l1 * 8;
    const int d0 = ci0 * 8, d1 = ci1 * 8;     // linear LDS dest (shorts)

#define STAGE_A(u) { const int so_ = ((u) & 3) * 8192; \
    gload_lds16(A + gA0 + (u) * 32, ldsA + so_ + d0);  \
    gload_lds16(A + gA1 + (u) * 32, ldsA + so_ + d1); }
#define STAGE_B(u) { const int so_ = ((u) & 3) * 8192; \
    gload_lds16(B + gB0 + (u) * 32, ldsB + so_ + d0);  \
    gload_lds16(B + gB1 + (u) * 32, ldsB + so_ + d1); }

    // ---- ds_read offsets (shorts within slot), swizzled chunk ----
    int offA[8], offBn[4];
#pragma unroll
    for (int f = 0; f < 8; ++f) {
        int r = wr * 128 + f * 16 + lr;
        offA[f] = r * 32 + ((kc ^ ((r >> 1) & 3)) * 8);
    }
#pragma unroll
    for (int n = 0; n < 4; ++n) {
        int r = wc * 64 + n * 16 + lr;
        offBn[n] = r * 32 + ((kc ^ ((r >> 1) & 3)) * 8);
    }

    f32x4 acc[8][4];
#pragma unroll
    for (int i = 0; i < 8; ++i)
#pragma unroll
        for (int j = 0; j < 4; ++j)
            acc[i][j] = (f32x4){0.f, 0.f, 0.f, 0.f};

    // ---- prologue: granules A0,B0,A1,B1,A2; wait tile0 landed ----
    STAGE_A(0); STAGE_B(0); STAGE_A(1); STAGE_B(1); STAGE_A(2);
    asm volatile("s_waitcnt vmcnt(6)" ::: "memory");
    __builtin_amdgcn_s_barrier();

#pragma unroll 4
    for (int T = 0; T < GNT; ++T) {
        const int so = (T & 3) * 8192;
        bf16x8 a0, a1, a2, a3, b0, b1, b2, b3;

        // ================= phase 0: m-frags 0-3 x all n =================
        a0 = *(const bf16x8*)&ldsA[so + offA[0]];
        a1 = *(const bf16x8*)&ldsA[so + offA[1]];
        a2 = *(const bf16x8*)&ldsA[so + offA[2]];
        a3 = *(const bf16x8*)&ldsA[so + offA[3]];
        b0 = *(const bf16x8*)&ldsB[so + offBn[0]];
        b1 = *(const bf16x8*)&ldsB[so + offBn[1]];
        b2 = *(const bf16x8*)&ldsB[so + offBn[2]];
        b3 = *(const bf16x8*)&ldsB[so + offBn[3]];
        if (T + 2 < GNT) STAGE_B(T + 2);
        __builtin_amdgcn_s_barrier();
        asm volatile("s_waitcnt lgkmcnt(0)" ::: "memory");
        __builtin_amdgcn_sched_barrier(0);
        __builtin_amdgcn_s_setprio(1);
        acc[0][0] = __builtin_amdgcn_mfma_f32_16x16x32_bf16(a0, b0, acc[0][0], 0, 0, 0);
        acc[0][1] = __builtin_amdgcn_mfma_f32_16x16x32_bf16(a0, b1, acc[0][1], 0, 0, 0);
        acc[0][2] = __builtin_amdgcn_mfma_f32_16x16x32_bf16(a0, b2, acc[0][2], 0, 0, 0);
        acc[0][3] = __builtin_amdgcn_mfma_f32_16x16x32_bf16(a0, b3, acc[0][3], 0, 0, 0);
        acc[1][0] = __builtin_amdgcn_mfma_f32_16x16x32_bf16(a1, b0, acc[1][0], 0, 0, 0);
        acc[1][1] = __builtin_amdgcn_mfma_f32_16x16x32_bf16(a1, b1, acc[1][1], 0, 0, 0);
        acc[1][2] = __builtin_amdgcn_mfma_f32_16x16x32_bf16(a1, b2, acc[1][2], 0, 0, 0);
        acc[1][3] = __builtin_amdgcn_mfma_f32_16x16x32_bf16(a1, b3, acc[1][3], 0, 0, 0);
        acc[2][0] = __builtin_amdgcn_mfma_f32_16x16x32_bf16(a2, b0, acc[2][0], 0, 0, 0);
        acc[2][1] = __builtin_amdgcn_mfma_f32_16x16x32_bf16(a2, b1, acc[2][1], 0, 0, 0);
        acc[2][2] = __builtin_amdgcn_mfma_f32_16x16x32_bf16(a2, b2, acc[2][2], 0, 0, 0);
        acc[2][3] = __builtin_amdgcn_mfma_f32_16x16x32_bf16(a2, b3, acc[2][3], 0, 0, 0);
        acc[3][0] = __builtin_amdgcn_mfma_f32_16x16x32_bf16(a3, b0, acc[3][0], 0, 0, 0);
        acc[3][1] = __builtin_amdgcn_mfma_f32_16x16x32_bf16(a3, b1, acc[3][1], 0, 0, 0);
        acc[3][2] = __builtin_amdgcn_mfma_f32_16x16x32_bf16(a3, b2, acc[3][2], 0, 0, 0);
        acc[3][3] = __builtin_amdgcn_mfma_f32_16x16x32_bf16(a3, b3, acc[3][3], 0, 0, 0);
        __builtin_amdgcn_s_setprio(0);
        __builtin_amdgcn_s_barrier();

        // ================= phase 1: m-frags 4-7 x all n =================
        a0 = *(const bf16x8*)&ldsA[so + offA[4]];
        a1 = *(const bf16x8*)&ldsA[so + offA[5]];
        a2 = *(const bf16x8*)&ldsA[so + offA[6]];
        a3 = *(const bf16x8*)&ldsA[so + offA[7]];
        if (T + 3 < GNT) STAGE_A(T + 3);
        __builtin_amdgcn_s_barrier();
        asm volatile("s_waitcnt lgkmcnt(0)" ::: "memory");
        __builtin_amdgcn_sched_barrier(0);
        __builtin_amdgcn_s_setprio(1);
        acc[4][0] = __builtin_amdgcn_mfma_f32_16x16x32_bf16(a0, b0, acc[4][0], 0, 0, 0);
        acc[4][1] = __builtin_amdgcn_mfma_f32_16x16x32_bf16(a0, b1, acc[4][1], 0, 0, 0);
        acc[4][2] = __builtin_amdgcn_mfma_f32_16x16x32_bf16(a0, b2, acc[4][2], 0, 0, 0);
        acc[4][3] = __builtin_amdgcn_mfma_f32_16x16x32_bf16(a0, b3, acc[4][3], 0, 0, 0);
        acc[5][0] = __builtin_amdgcn_mfma_f32_16x16x32_bf16(a1, b0, acc[5][0], 0, 0, 0);
        acc[5][1] = __builtin_amdgcn_mfma_f32_16x16x32_bf16(a1, b1, acc[5][1], 0, 0, 0);
        acc[5][2] = __builtin_amdgcn_mfma_f32_16x16x32_bf16(a1, b2, acc[5][2], 0, 0, 0);
        acc[5][3] = __builtin_amdgcn_mfma_f32_16x16x32_bf16(a1, b3, acc[5][3], 0, 0, 0);
        acc[6][0] = __builtin_amdgcn_mfma_f32_16x16x32_bf16(a2, b0, acc[6][0], 0, 0, 0);
        acc[6][1] = __builtin_amdgcn_mfma_f32_16x16x32_bf16(a2, b1, acc[6][1], 0, 0, 0);
        acc[6][2] = __builtin_amdgcn_mfma_f32_16x16x32_bf16(a2, b2, acc[6][2], 0, 0, 0);
        acc[6][3] = __builtin_amdgcn_mfma_f32_16x16x32_bf16(a2, b3, acc[6][3], 0, 0, 0);
        acc[7][0] = __builtin_amdgcn_mfma_f32_16x16x32_bf16(a3, b0, acc[7][0], 0, 0, 0);
        acc[7][1] = __builtin_amdgcn_mfma_f32_16x16x32_bf16(a3, b1, acc[7][1], 0, 0, 0);
        acc[7][2] = __builtin_amdgcn_mfma_f32_16x16x32_bf16(a3, b2, acc[7][2], 0, 0, 0);
        acc[7][3] = __builtin_amdgcn_mfma_f32_16x16x32_bf16(a3, b3, acc[7][3], 0, 0, 0);
        __builtin_amdgcn_s_setprio(0);
        // counted vmcnt: tiles T+1 granules landed; drain 6 -> 4 -> 0 at tail
        if (T < GNT - 3)      { asm volatile("s_waitcnt vmcnt(6)" ::: "memory"); }
        else if (T == GNT - 3){ asm volatile("s_waitcnt vmcnt(4)" ::: "memory"); }
        else if (T == GNT - 2){ asm volatile("s_waitcnt vmcnt(0)" ::: "memory"); }
        __builtin_amdgcn_s_barrier();
    }

    // ---- epilogue: C/D layout col=lane&15, row=(lane>>4)*4+reg ----
    const int crow = brow + wr * 128 + kc * 4;
    const int ccol = bcol + wc * 64 + lr;
#pragma unroll
    for (int ai = 0; ai < 8; ++ai)
#pragma unroll
        for (int in = 0; in < 4; ++in)
#pragma unroll
            for (int r = 0; r < 4; ++r)
                C[(size_t)(crow + ai * 16 + r) * N + ccol + in * 16] = acc[ai][in][r];
#undef STAGE_A
#undef STAGE_B
}

// ---------------- fused LN + LSTM pointwise ----------------
__global__ __launch_bounds__(256) void ln_lstm(
    const float* __restrict__ i2h, const float* __restrict__ h2h,
    const float* __restrict__ cx, const float* __restrict__ b_hh,
    const float* __restrict__ g_ih, const float* __restrict__ be_ih,
    const float* __restrict__ g_hh, const float* __restrict__ be_hh,
    const float* __restrict__ g_ho, const float* __restrict__ be_ho,
    float* __restrict__ hy, float* __restrict__ cy, int H)
{
    const int b = blockIdx.x;
    const int t = threadIdx.x;
    const int lane = t & 63;
    const int wave = t >> 6;
    const int H4 = 4 * H;

    const float* xi = i2h + (size_t)b * H4;
    const float* xh = h2h + (size_t)b * H4;

    __shared__ float red[4][4];

    float si = 0.f, qi = 0.f, sh = 0.f, qh = 0.f;
    for (int j = t * 4; j < H4; j += 256 * 4) {
        float4 vi = *reinterpret_cast<const float4*>(xi + j);
        float4 vh = *reinterpret_cast<const float4*>(xh + j);
        float4 vb = *reinterpret_cast<const float4*>(b_hh + j);
        si += vi.x + vi.y + vi.z + vi.w;
        qi += vi.x * vi.x + vi.y * vi.y + vi.z * vi.z + vi.w * vi.w;
        float h0 = vh.x + vb.x, h1 = vh.y + vb.y, h2 = vh.z + vb.z, h3 = vh.w + vb.w;
        sh += h0 + h1 + h2 + h3;
        qh += h0 * h0 + h1 * h1 + h2 * h2 + h3 * h3;
    }
    si = wred(si); qi = wred(qi); sh = wred(sh); qh = wred(qh);
    if (lane == 0) { red[wave][0] = si; red[wave][1] = qi; red[wave][2] = sh; red[wave][3] = qh; }
    __syncthreads();
    float Si = red[0][0] + red[1][0] + red[2][0] + red[3][0];
    float Qi = red[0][1] + red[1][1] + red[2][1] + red[3][1];
    float Sh = red[0][2] + red[1][2] + red[2][2] + red[3][2];
    float Qh = red[0][3] + red[1][3] + red[2][3] + red[3][3];
    const float inv4H = 1.0f / (float)H4;
    float mi = Si * inv4H, mh = Sh * inv4H;
    float ri = rsqrtf(Qi * inv4H - mi * mi + LN_EPS);
    float rh = rsqrtf(Qh * inv4H - mh * mh + LN_EPS);

    float tv[4], ov[4];
    float s2 = 0.f, q2 = 0.f;
#pragma unroll
    for (int u = 0; u < 4; ++u) {
        const int h = t + u * 256;
        const int ji = h, jf = H + h, jo = 2 * H + h, jg = 3 * H + h;
        float gi = (xi[ji] - mi) * ri * g_ih[ji] + be_ih[ji]
                 + (xh[ji] + b_hh[ji] - mh) * rh * g_hh[ji] + be_hh[ji];
        float gf = (xi[jf] - mi) * ri * g_ih[jf] + be_ih[jf]
                 + (xh[jf] + b_hh[jf] - mh) * rh * g_hh[jf] + be_hh[jf];
        float go = (xi[jo] - mi) * ri * g_ih[jo] + be_ih[jo]
                 + (xh[jo] + b_hh[jo] - mh) * rh * g_hh[jo] + be_hh[jo];
        float gg = (xi[jg] - mi) * ri * g_ih[jg] + be_ih[jg]
                 + (xh[jg] + b_hh[jg] - mh) * rh * g_hh[jg] + be_hh[jg];
        float c = sigf(gf) * cx[(size_t)b * H + h] + sigf(gi) * tanh_fast(gg);
        cy[(size_t)b * H + h] = c;
        float tc = tanh_fast(c);
        tv[u] = tc; ov[u] = sigf(go);
        s2 += tc; q2 += tc * tc;
    }
    s2 = wred(s2); q2 = wred(q2);
    __syncthreads();
    if (lane == 0) { red[wave][0] = s2; red[wave][1] = q2; }
    __syncthreads();
    float S2 = red[0][0] + red[1][0] + red[2][0] + red[3][0];
    float Q2 = red[0][1] + red[1][1] + red[2][1] + red[3][1];
    const float invH = 1.0f / (float)H;
    float mt = S2 * invH;
    float rt = rsqrtf(Q2 * invH - mt * mt + LN_EPS);
#pragma unroll
    for (int u = 0; u < 4; ++u) {
        const int h = t + u * 256;
        hy[(size_t)b * H + h] = ov[u] * ((tv[u] - mt) * rt * g_ho[h] + be_ho[h]);
    }
}

// ---------------- launcher ----------------
extern "C" void kernel_launch(void* const* d_in, const int* in_sizes, int n_in,
                              void* d_out, int out_size, void* d_ws, size_t ws_size,
                              hipStream_t stream) {
    const float* inputs  = (const float*)d_in[0];
    const float* hx      = (const float*)d_in[1];
    const float* cx      = (const float*)d_in[2];
    const float* w_ih    = (const float*)d_in[3];
    const float* w_hh    = (const float*)d_in[4];
    const float* b_hh    = (const float*)d_in[5];
    const float* g_ih    = (const float*)d_in[6];
    const float* beta_ih = (const float*)d_in[7];
    const float* g_hh    = (const float*)d_in[8];
    const float* beta_hh = (const float*)d_in[9];
    const float* g_ho    = (const float*)d_in[10];
    const float* beta_ho = (const float*)d_in[11];

    const int H  = in_sizes[10];            // 1024
    const int B  = in_sizes[1] / H;         // 4096
    const int D  = in_sizes[0] / B;         // 1024
    const int H4 = 4 * H;

    uint8_t* ws = (uint8_t*)d_ws;
    size_t off = 0;
    short* Abf  = (short*)(ws + off); off += (size_t)B * D * 2;
    short* Hbf  = (short*)(ws + off); off += (size_t)B * H * 2;
    short* Wih  = (short*)(ws + off); off += (size_t)H4 * D * 2;
    short* Whh  = (short*)(ws + off); off += (size_t)H4 * H * 2;
    float* i2h  = (float*)(ws + off); off += (size_t)B * H4 * 4;
    float* h2h  = (float*)(ws + off); off += (size_t)B * H4 * 4;

    float* hy = (float*)d_out;
    float* cyo = (float*)d_out + (size_t)B * H;

    // 1) casts
    {
        int n4 = (B * D) / 4;
        cast_kernel<<<(n4 + 255) / 256, 256, 0, stream>>>((const float4*)inputs, (ushort4*)Abf, n4);
        n4 = (B * H) / 4;
        cast_kernel<<<(n4 + 255) / 256, 256, 0, stream>>>((const float4*)hx, (ushort4*)Hbf, n4);
        n4 = (H4 * D) / 4;
        cast_kernel<<<(n4 + 255) / 256, 256, 0, stream>>>((const float4*)w_ih, (ushort4*)Wih, n4);
        n4 = (H4 * H) / 4;
        cast_kernel<<<(n4 + 255) / 256, 256, 0, stream>>>((const float4*)w_hh, (ushort4*)Whh, n4);
    }

    // 2) both GEMMs in one pipelined 256^2 launch (z selects)
    {
        dim3 grid(H4 / 256, B / 256, 2);
        gemm8p<<<grid, 512, 0, stream>>>(Abf, Wih, i2h, Hbf, Whh, h2h, H4, D);
    }

    // 3) fused LN + LSTM
    ln_lstm<<<B, 256, 0, stream>>>(i2h, h2h, cx, b_hh, g_ih, beta_ih, g_hh, beta_hh,
                                   g_ho, beta_ho, hy, cyo, H);
}

// Round 3
// 136.613 us; speedup vs baseline: 1.3611x; 1.2155x over previous
//
#include <hip/hip_runtime.h>
#include <hip/hip_bf16.h>
#include <stdint.h>

typedef __attribute__((ext_vector_type(8))) short bf16x8;
typedef __attribute__((ext_vector_type(4))) float f32x4;

#define LN_EPS 1e-5f

// ---------------- helpers ----------------
__device__ inline unsigned short f2bf(float f) {
    unsigned u = __builtin_bit_cast(unsigned, f);
    u += 0x7fffu + ((u >> 16) & 1u);          // RNE
    return (unsigned short)(u >> 16);
}
__device__ inline float bf2f(unsigned short u) {
    return __builtin_bit_cast(float, ((unsigned)u) << 16);
}
__device__ inline float sigf(float x) {
    return 1.0f / (1.0f + __expf(-x));
}
__device__ inline float tanh_fast(float x) {
    return __builtin_fmaf(2.0f, 1.0f / (1.0f + __expf(-2.0f * x)), -1.0f);
}
__device__ inline float wred(float v) {
#pragma unroll
    for (int o = 32; o > 0; o >>= 1) v += __shfl_xor(v, o);
    return v;
}
__device__ inline void gload_lds16(const void* g, void* l) {
    __builtin_amdgcn_global_load_lds(
        (const __attribute__((address_space(1))) void*)g,
        (__attribute__((address_space(3))) void*)l, 16, 0, 0);
}

// ---------------- cast f32 -> bf16 ----------------
__global__ __launch_bounds__(256) void cast_kernel(const float4* __restrict__ src,
                                                   ushort4* __restrict__ dst, int n4) {
    int i = blockIdx.x * blockDim.x + threadIdx.x;
    if (i < n4) {
        float4 v = src[i];
        ushort4 o;
        o.x = f2bf(v.x); o.y = f2bf(v.y); o.z = f2bf(v.z); o.w = f2bf(v.w);
        dst[i] = o;
    }
}

// =====================================================================
// 256x256 bf16 NT GEMM, pipelined (ring-4 LDS, counted vmcnt, setprio,
// XOR chunk swizzle, bijective XCD swizzle). Epilogue: +bias (z=1),
// bf16 C store, per-row partial (sum, sumsq) of the ROUNDED values -> P.
// =====================================================================
#define GNT 32   // K/32

__global__ __launch_bounds__(512) void gemm8p(
    const short* __restrict__ Aa, const short* __restrict__ Ba, unsigned short* __restrict__ Ca,
    const short* __restrict__ Ab, const short* __restrict__ Bb, unsigned short* __restrict__ Cb,
    const float* __restrict__ Bias,   // b_hh, used when z==1
    float2* __restrict__ P,           // [2][16][256][16] per-row partial stats
    int N, int K)
{
    __shared__ __attribute__((aligned(16))) short lds[65536];  // 128 KiB
    short* ldsA = lds;
    short* ldsB = lds + 32768;

    // ---- T1: bijective XCD swizzle over 512 blocks ----
    const int gx  = gridDim.x;            // 16
    const int gxy = gx * gridDim.y;       // 256
    int bid = (blockIdx.z * gridDim.y + blockIdx.y) * gx + blockIdx.x;
    const int cpx = (gxy * gridDim.z) >> 3;   // 64
    int swz = (bid & 7) * cpx + (bid >> 3);
    const int z  = swz / gxy;
    const int r2 = swz - z * gxy;
    const int by = r2 / gx;
    const int bx = r2 - by * gx;

    const short* __restrict__ A = z ? Ab : Aa;
    const short* __restrict__ B = z ? Bb : Ba;
    unsigned short* __restrict__ C = z ? Cb : Ca;
    const int brow = by * 256, bcol = bx * 256;

    const int t    = threadIdx.x;
    const int lane = t & 63, w = t >> 6;
    const int wr = w >> 2, wc = w & 3;    // 2x4 wave grid; wave tile 128x64
    const int lr = lane & 15, kc = lane >> 4;

    // ---- staging addresses ----
    const int ci0 = t, ci1 = t + 512;
    const int r0 = ci0 >> 2, l0 = (ci0 & 3) ^ ((r0 >> 1) & 3);
    const int r1 = ci1 >> 2, l1 = (ci1 & 3) ^ ((r1 >> 1) & 3);
    const int gA0 = (brow + r0) * K + l0 * 8;
    const int gA1 = (brow + r1) * K + l1 * 8;
    const int gB0 = (bcol + r0) * K + l0 * 8;
    const int gB1 = (bcol + r1) * K + l1 * 8;
    const int d0 = ci0 * 8, d1 = ci1 * 8;

#define STAGE_A(u) { const int so_ = ((u) & 3) * 8192; \
    gload_lds16(A + gA0 + (u) * 32, ldsA + so_ + d0);  \
    gload_lds16(A + gA1 + (u) * 32, ldsA + so_ + d1); }
#define STAGE_B(u) { const int so_ = ((u) & 3) * 8192; \
    gload_lds16(B + gB0 + (u) * 32, ldsB + so_ + d0);  \
    gload_lds16(B + gB1 + (u) * 32, ldsB + so_ + d1); }

    int offA[8], offBn[4];
#pragma unroll
    for (int f = 0; f < 8; ++f) {
        int r = wr * 128 + f * 16 + lr;
        offA[f] = r * 32 + ((kc ^ ((r >> 1) & 3)) * 8);
    }
#pragma unroll
    for (int n = 0; n < 4; ++n) {
        int r = wc * 64 + n * 16 + lr;
        offBn[n] = r * 32 + ((kc ^ ((r >> 1) & 3)) * 8);
    }

    f32x4 acc[8][4];
#pragma unroll
    for (int i = 0; i < 8; ++i)
#pragma unroll
        for (int j = 0; j < 4; ++j)
            acc[i][j] = (f32x4){0.f, 0.f, 0.f, 0.f};

    STAGE_A(0); STAGE_B(0); STAGE_A(1); STAGE_B(1); STAGE_A(2);
    asm volatile("s_waitcnt vmcnt(6)" ::: "memory");
    __builtin_amdgcn_s_barrier();

#pragma unroll 4
    for (int T = 0; T < GNT; ++T) {
        const int so = (T & 3) * 8192;
        bf16x8 a0, a1, a2, a3, b0, b1, b2, b3;

        // ---- phase 0: m-frags 0-3 ----
        a0 = *(const bf16x8*)&ldsA[so + offA[0]];
        a1 = *(const bf16x8*)&ldsA[so + offA[1]];
        a2 = *(const bf16x8*)&ldsA[so + offA[2]];
        a3 = *(const bf16x8*)&ldsA[so + offA[3]];
        b0 = *(const bf16x8*)&ldsB[so + offBn[0]];
        b1 = *(const bf16x8*)&ldsB[so + offBn[1]];
        b2 = *(const bf16x8*)&ldsB[so + offBn[2]];
        b3 = *(const bf16x8*)&ldsB[so + offBn[3]];
        if (T + 2 < GNT) STAGE_B(T + 2);
        __builtin_amdgcn_s_barrier();
        asm volatile("s_waitcnt lgkmcnt(0)" ::: "memory");
        __builtin_amdgcn_sched_barrier(0);
        __builtin_amdgcn_s_setprio(1);
        acc[0][0] = __builtin_amdgcn_mfma_f32_16x16x32_bf16(a0, b0, acc[0][0], 0, 0, 0);
        acc[0][1] = __builtin_amdgcn_mfma_f32_16x16x32_bf16(a0, b1, acc[0][1], 0, 0, 0);
        acc[0][2] = __builtin_amdgcn_mfma_f32_16x16x32_bf16(a0, b2, acc[0][2], 0, 0, 0);
        acc[0][3] = __builtin_amdgcn_mfma_f32_16x16x32_bf16(a0, b3, acc[0][3], 0, 0, 0);
        acc[1][0] = __builtin_amdgcn_mfma_f32_16x16x32_bf16(a1, b0, acc[1][0], 0, 0, 0);
        acc[1][1] = __builtin_amdgcn_mfma_f32_16x16x32_bf16(a1, b1, acc[1][1], 0, 0, 0);
        acc[1][2] = __builtin_amdgcn_mfma_f32_16x16x32_bf16(a1, b2, acc[1][2], 0, 0, 0);
        acc[1][3] = __builtin_amdgcn_mfma_f32_16x16x32_bf16(a1, b3, acc[1][3], 0, 0, 0);
        acc[2][0] = __builtin_amdgcn_mfma_f32_16x16x32_bf16(a2, b0, acc[2][0], 0, 0, 0);
        acc[2][1] = __builtin_amdgcn_mfma_f32_16x16x32_bf16(a2, b1, acc[2][1], 0, 0, 0);
        acc[2][2] = __builtin_amdgcn_mfma_f32_16x16x32_bf16(a2, b2, acc[2][2], 0, 0, 0);
        acc[2][3] = __builtin_amdgcn_mfma_f32_16x16x32_bf16(a2, b3, acc[2][3], 0, 0, 0);
        acc[3][0] = __builtin_amdgcn_mfma_f32_16x16x32_bf16(a3, b0, acc[3][0], 0, 0, 0);
        acc[3][1] = __builtin_amdgcn_mfma_f32_16x16x32_bf16(a3, b1, acc[3][1], 0, 0, 0);
        acc[3][2] = __builtin_amdgcn_mfma_f32_16x16x32_bf16(a3, b2, acc[3][2], 0, 0, 0);
        acc[3][3] = __builtin_amdgcn_mfma_f32_16x16x32_bf16(a3, b3, acc[3][3], 0, 0, 0);
        __builtin_amdgcn_s_setprio(0);
        __builtin_amdgcn_s_barrier();

        // ---- phase 1: m-frags 4-7 ----
        a0 = *(const bf16x8*)&ldsA[so + offA[4]];
        a1 = *(const bf16x8*)&ldsA[so + offA[5]];
        a2 = *(const bf16x8*)&ldsA[so + offA[6]];
        a3 = *(const bf16x8*)&ldsA[so + offA[7]];
        if (T + 3 < GNT) STAGE_A(T + 3);
        __builtin_amdgcn_s_barrier();
        asm volatile("s_waitcnt lgkmcnt(0)" ::: "memory");
        __builtin_amdgcn_sched_barrier(0);
        __builtin_amdgcn_s_setprio(1);
        acc[4][0] = __builtin_amdgcn_mfma_f32_16x16x32_bf16(a0, b0, acc[4][0], 0, 0, 0);
        acc[4][1] = __builtin_amdgcn_mfma_f32_16x16x32_bf16(a0, b1, acc[4][1], 0, 0, 0);
        acc[4][2] = __builtin_amdgcn_mfma_f32_16x16x32_bf16(a0, b2, acc[4][2], 0, 0, 0);
        acc[4][3] = __builtin_amdgcn_mfma_f32_16x16x32_bf16(a0, b3, acc[4][3], 0, 0, 0);
        acc[5][0] = __builtin_amdgcn_mfma_f32_16x16x32_bf16(a1, b0, acc[5][0], 0, 0, 0);
        acc[5][1] = __builtin_amdgcn_mfma_f32_16x16x32_bf16(a1, b1, acc[5][1], 0, 0, 0);
        acc[5][2] = __builtin_amdgcn_mfma_f32_16x16x32_bf16(a1, b2, acc[5][2], 0, 0, 0);
        acc[5][3] = __builtin_amdgcn_mfma_f32_16x16x32_bf16(a1, b3, acc[5][3], 0, 0, 0);
        acc[6][0] = __builtin_amdgcn_mfma_f32_16x16x32_bf16(a2, b0, acc[6][0], 0, 0, 0);
        acc[6][1] = __builtin_amdgcn_mfma_f32_16x16x32_bf16(a2, b1, acc[6][1], 0, 0, 0);
        acc[6][2] = __builtin_amdgcn_mfma_f32_16x16x32_bf16(a2, b2, acc[6][2], 0, 0, 0);
        acc[6][3] = __builtin_amdgcn_mfma_f32_16x16x32_bf16(a2, b3, acc[6][3], 0, 0, 0);
        acc[7][0] = __builtin_amdgcn_mfma_f32_16x16x32_bf16(a3, b0, acc[7][0], 0, 0, 0);
        acc[7][1] = __builtin_amdgcn_mfma_f32_16x16x32_bf16(a3, b1, acc[7][1], 0, 0, 0);
        acc[7][2] = __builtin_amdgcn_mfma_f32_16x16x32_bf16(a3, b2, acc[7][2], 0, 0, 0);
        acc[7][3] = __builtin_amdgcn_mfma_f32_16x16x32_bf16(a3, b3, acc[7][3], 0, 0, 0);
        __builtin_amdgcn_s_setprio(0);
        if (T < GNT - 3)      { asm volatile("s_waitcnt vmcnt(6)" ::: "memory"); }
        else if (T == GNT - 3){ asm volatile("s_waitcnt vmcnt(4)" ::: "memory"); }
        else if (T == GNT - 2){ asm volatile("s_waitcnt vmcnt(0)" ::: "memory"); }
        __builtin_amdgcn_s_barrier();
    }

    // ---- epilogue: +bias (z=1), bf16 store, per-row partial stats ----
    const int crow = wr * 128 + kc * 4;   // local row base for this lane
    const int ccol = wc * 64 + lr;        // local col base for this lane
    float bias[4];
#pragma unroll
    for (int in = 0; in < 4; ++in)
        bias[in] = z ? Bias[bcol + ccol + in * 16] : 0.f;

    __syncthreads();                       // tiles no longer needed; reuse LDS
    float2* part = (float2*)lds;           // [4 (wc)][256 rows]

#pragma unroll
    for (int ai = 0; ai < 8; ++ai) {
        float rs[4] = {0.f, 0.f, 0.f, 0.f};
        float rq[4] = {0.f, 0.f, 0.f, 0.f};
#pragma unroll
        for (int in = 0; in < 4; ++in) {
#pragma unroll
            for (int r = 0; r < 4; ++r) {
                float v = acc[ai][in][r] + bias[in];
                unsigned short us = f2bf(v);
                float vf = bf2f(us);
                C[(size_t)(brow + crow + ai * 16 + r) * N + bcol + ccol + in * 16] = us;
                rs[r] += vf; rq[r] += vf * vf;
            }
        }
#pragma unroll
        for (int r = 0; r < 4; ++r) {
            float s = rs[r], q = rq[r];
#pragma unroll
            for (int o = 8; o > 0; o >>= 1) { s += __shfl_xor(s, o); q += __shfl_xor(q, o); }
            if (lr == 0) {
                float2 pr; pr.x = s; pr.y = q;
                part[wc * 256 + crow + ai * 16 + r] = pr;
            }
        }
    }
    __syncthreads();
    if (t < 256) {
        float2 a0 = part[t], a1 = part[256 + t], a2 = part[512 + t], a3 = part[768 + t];
        float2 o; o.x = a0.x + a1.x + a2.x + a3.x; o.y = a0.y + a1.y + a2.y + a3.y;
        P[((size_t)(z * 16 + by) * 256 + t) * 16 + bx] = o;
    }
#undef STAGE_A
#undef STAGE_B
}

// ---------------- fold 16 col-block partials -> (mean, rstd) per row ----------------
__global__ __launch_bounds__(256) void reduce_stats(const float2* __restrict__ P,
                                                    float2* __restrict__ stats, float invn) {
    const int row = blockIdx.x * 256 + threadIdx.x;   // 0..8191
    float s = 0.f, q = 0.f;
#pragma unroll
    for (int b = 0; b < 16; ++b) { float2 v = P[(size_t)row * 16 + b]; s += v.x; q += v.y; }
    float m = s * invn;
    float r = rsqrtf(q * invn - m * m + LN_EPS);
    float2 o; o.x = m; o.y = r;
    stats[row] = o;
}

// ---------------- single-pass LN + LSTM pointwise ----------------
__global__ __launch_bounds__(256) void ln_lstm(
    const unsigned short* __restrict__ i2h,   // [B,4H] bf16 (rounded)
    const unsigned short* __restrict__ h2h,   // [B,4H] bf16 (bias included)
    const float* __restrict__ cx,
    const float2* __restrict__ statsI, const float2* __restrict__ statsH,
    const float* __restrict__ g_ih, const float* __restrict__ be_ih,
    const float* __restrict__ g_hh, const float* __restrict__ be_hh,
    const float* __restrict__ g_ho, const float* __restrict__ be_ho,
    float* __restrict__ hy, float* __restrict__ cy, int H)
{
    const int b = blockIdx.x;
    const int t = threadIdx.x;
    const int lane = t & 63;
    const int wave = t >> 6;
    const int H4 = 4 * H;
    const int h0 = t * 4;

    const unsigned short* xi = i2h + (size_t)b * H4;
    const unsigned short* xh = h2h + (size_t)b * H4;

    const float2 sI = statsI[b];
    const float2 sH = statsH[b];

    __shared__ float red[4][2];

    float gate[4][4];
#pragma unroll
    for (int q = 0; q < 4; ++q) {
        const int j = q * H + h0;
        ushort4 vi = *reinterpret_cast<const ushort4*>(&xi[j]);
        ushort4 vh = *reinterpret_cast<const ushort4*>(&xh[j]);
        float4 gi = *reinterpret_cast<const float4*>(&g_ih[j]);
        float4 bi = *reinterpret_cast<const float4*>(&be_ih[j]);
        float4 gh = *reinterpret_cast<const float4*>(&g_hh[j]);
        float4 bh = *reinterpret_cast<const float4*>(&be_hh[j]);
        gate[q][0] = (bf2f(vi.x) - sI.x) * sI.y * gi.x + bi.x + (bf2f(vh.x) - sH.x) * sH.y * gh.x + bh.x;
        gate[q][1] = (bf2f(vi.y) - sI.x) * sI.y * gi.y + bi.y + (bf2f(vh.y) - sH.x) * sH.y * gh.y + bh.y;
        gate[q][2] = (bf2f(vi.z) - sI.x) * sI.y * gi.z + bi.z + (bf2f(vh.z) - sH.x) * sH.y * gh.z + bh.z;
        gate[q][3] = (bf2f(vi.w) - sI.x) * sI.y * gi.w + bi.w + (bf2f(vh.w) - sH.x) * sH.y * gh.w + bh.w;
    }

    float4 cxv = *reinterpret_cast<const float4*>(&cx[(size_t)b * H + h0]);
    float cvals[4] = {cxv.x, cxv.y, cxv.z, cxv.w};
    float tv[4], ov[4];
    float s2 = 0.f, q2 = 0.f;
    float4 cyv;
#pragma unroll
    for (int k = 0; k < 4; ++k) {
        float c = sigf(gate[1][k]) * cvals[k] + sigf(gate[0][k]) * tanh_fast(gate[3][k]);
        ((float*)&cyv)[k] = c;
        float tc = tanh_fast(c);
        tv[k] = tc; ov[k] = sigf(gate[2][k]);
        s2 += tc; q2 += tc * tc;
    }
    *reinterpret_cast<float4*>(&cy[(size_t)b * H + h0]) = cyv;

    s2 = wred(s2); q2 = wred(q2);
    if (lane == 0) { red[wave][0] = s2; red[wave][1] = q2; }
    __syncthreads();
    float S2 = red[0][0] + red[1][0] + red[2][0] + red[3][0];
    float Q2 = red[0][1] + red[1][1] + red[2][1] + red[3][1];
    const float invH = 1.0f / (float)H;
    float mt = S2 * invH;
    float rt = rsqrtf(Q2 * invH - mt * mt + LN_EPS);

    float4 go = *reinterpret_cast<const float4*>(&g_ho[h0]);
    float4 bo = *reinterpret_cast<const float4*>(&be_ho[h0]);
    float4 hyv;
    hyv.x = ov[0] * ((tv[0] - mt) * rt * go.x + bo.x);
    hyv.y = ov[1] * ((tv[1] - mt) * rt * go.y + bo.y);
    hyv.z = ov[2] * ((tv[2] - mt) * rt * go.z + bo.z);
    hyv.w = ov[3] * ((tv[3] - mt) * rt * go.w + bo.w);
    *reinterpret_cast<float4*>(&hy[(size_t)b * H + h0]) = hyv;
}

// ---------------- launcher ----------------
extern "C" void kernel_launch(void* const* d_in, const int* in_sizes, int n_in,
                              void* d_out, int out_size, void* d_ws, size_t ws_size,
                              hipStream_t stream) {
    const float* inputs  = (const float*)d_in[0];
    const float* hx      = (const float*)d_in[1];
    const float* cx      = (const float*)d_in[2];
    const float* w_ih    = (const float*)d_in[3];
    const float* w_hh    = (const float*)d_in[4];
    const float* b_hh    = (const float*)d_in[5];
    const float* g_ih    = (const float*)d_in[6];
    const float* beta_ih = (const float*)d_in[7];
    const float* g_hh    = (const float*)d_in[8];
    const float* beta_hh = (const float*)d_in[9];
    const float* g_ho    = (const float*)d_in[10];
    const float* beta_ho = (const float*)d_in[11];

    const int H  = in_sizes[10];            // 1024
    const int B  = in_sizes[1] / H;         // 4096
    const int D  = in_sizes[0] / B;         // 1024
    const int H4 = 4 * H;

    uint8_t* ws = (uint8_t*)d_ws;
    size_t off = 0;
    short* Abf  = (short*)(ws + off); off += (size_t)B * D * 2;
    short* Hbf  = (short*)(ws + off); off += (size_t)B * H * 2;
    short* Wih  = (short*)(ws + off); off += (size_t)H4 * D * 2;
    short* Whh  = (short*)(ws + off); off += (size_t)H4 * H * 2;
    unsigned short* i2hb = (unsigned short*)(ws + off); off += (size_t)B * H4 * 2;
    unsigned short* h2hb = (unsigned short*)(ws + off); off += (size_t)B * H4 * 2;
    float2* P     = (float2*)(ws + off); off += (size_t)2 * 16 * 256 * 16 * sizeof(float2);
    float2* stats = (float2*)(ws + off); off += (size_t)2 * B * sizeof(float2);

    float* hy  = (float*)d_out;
    float* cyo = (float*)d_out + (size_t)B * H;

    // 1) casts
    {
        int n4 = (B * D) / 4;
        cast_kernel<<<(n4 + 255) / 256, 256, 0, stream>>>((const float4*)inputs, (ushort4*)Abf, n4);
        n4 = (B * H) / 4;
        cast_kernel<<<(n4 + 255) / 256, 256, 0, stream>>>((const float4*)hx, (ushort4*)Hbf, n4);
        n4 = (H4 * D) / 4;
        cast_kernel<<<(n4 + 255) / 256, 256, 0, stream>>>((const float4*)w_ih, (ushort4*)Wih, n4);
        n4 = (H4 * H) / 4;
        cast_kernel<<<(n4 + 255) / 256, 256, 0, stream>>>((const float4*)w_hh, (ushort4*)Whh, n4);
    }

    // 2) both GEMMs + fused LN-stats partials
    {
        dim3 grid(H4 / 256, B / 256, 2);
        gemm8p<<<grid, 512, 0, stream>>>(Abf, Wih, i2hb, Hbf, Whh, h2hb, b_hh, P, H4, D);
    }

    // 3) fold partials -> (mean, rstd) per row, both matrices
    reduce_stats<<<(2 * B) / 256, 256, 0, stream>>>(P, stats, 1.0f / (float)H4);

    // 4) single-pass LN + LSTM
    ln_lstm<<<B, 256, 0, stream>>>(i2hb, h2hb, cx, stats, stats + B,
                                   g_ih, beta_ih, g_hh, beta_hh, g_ho, beta_ho,
                                   hy, cyo, H);
}

// Round 4
// 127.797 us; speedup vs baseline: 1.4550x; 1.0690x over previous
//
#include <hip/hip_runtime.h>
#include <hip/hip_bf16.h>
#include <stdint.h>

typedef __attribute__((ext_vector_type(8))) short bf16x8;
typedef __attribute__((ext_vector_type(4))) float f32x4;

#define LN_EPS 1e-5f

// ---------------- helpers ----------------
__device__ inline unsigned f2bf(float f) {
    unsigned u = __builtin_bit_cast(unsigned, f);
    u += 0x7fffu + ((u >> 16) & 1u);          // RNE
    return u >> 16;
}
__device__ inline float bf2f(unsigned u) {
    return __builtin_bit_cast(float, u << 16);
}
__device__ inline float sigf(float x) {
    return 1.0f / (1.0f + __expf(-x));
}
__device__ inline float tanh_fast(float x) {
    return __builtin_fmaf(2.0f, 1.0f / (1.0f + __expf(-2.0f * x)), -1.0f);
}
__device__ inline float wred(float v) {
#pragma unroll
    for (int o = 32; o > 0; o >>= 1) v += __shfl_xor(v, o);
    return v;
}
__device__ inline void gload_lds16(const void* g, void* l) {
    __builtin_amdgcn_global_load_lds(
        (const __attribute__((address_space(1))) void*)g,
        (__attribute__((address_space(3))) void*)l, 16, 0, 0);
}

// ---------------- merged cast f32 -> bf16 (4 regions, 1 launch) ----------------
__global__ __launch_bounds__(256) void cast_all(
    const float4* __restrict__ s0, ushort4* __restrict__ d0, int n0,
    const float4* __restrict__ s1, ushort4* __restrict__ d1, int n1,
    const float4* __restrict__ s2, ushort4* __restrict__ d2, int n2,
    const float4* __restrict__ s3, ushort4* __restrict__ d3, int n3)
{
    int j = blockIdx.x * blockDim.x + threadIdx.x;
    const float4* s; ushort4* d;
    if (j < n0) { s = s0; d = d0; }
    else {
        j -= n0;
        if (j < n1) { s = s1; d = d1; }
        else {
            j -= n1;
            if (j < n2) { s = s2; d = d2; }
            else {
                j -= n2;
                if (j >= n3) return;
                s = s3; d = d3;
            }
        }
    }
    float4 v = s[j];
    ushort4 o;
    o.x = (unsigned short)f2bf(v.x); o.y = (unsigned short)f2bf(v.y);
    o.z = (unsigned short)f2bf(v.z); o.w = (unsigned short)f2bf(v.w);
    d[j] = o;
}

// =====================================================================
// 256x256 bf16 NT GEMM, pipelined (ring-4 LDS, counted vmcnt, setprio,
// XOR chunk swizzle, bijective XCD swizzle). SWAPPED-OPERAND MFMA:
// acc[f][n] = mfma(W_frag[f], X_frag[n]) so each lane holds 4 CONSECUTIVE
// gate cols (reg dim) at a fixed batch row -> packed 8B C-stores and
// in-lane LN-stat reduction. Epilogue: +bias (z=1), bf16 C, partials -> P.
// =====================================================================
#define GNT 32   // K/32

__global__ __launch_bounds__(512) void gemm8p(
    const short* __restrict__ Aa, const short* __restrict__ Ba, unsigned short* __restrict__ Ca,
    const short* __restrict__ Ab, const short* __restrict__ Bb, unsigned short* __restrict__ Cb,
    const float* __restrict__ Bias,   // b_hh, used when z==1
    float2* __restrict__ P,           // [2][16][256][16] per-row partial stats
    int N, int K)
{
    __shared__ __attribute__((aligned(16))) short lds[65536];  // 128 KiB
    short* ldsA = lds;            // batch tile: 4 slots x (256 rows x 32 k)
    short* ldsB = lds + 32768;    // weight tile: 4 slots

    // ---- T1: bijective XCD swizzle over 512 blocks ----
    const int gx  = gridDim.x;            // 16
    const int gxy = gx * gridDim.y;       // 256
    int bid = (blockIdx.z * gridDim.y + blockIdx.y) * gx + blockIdx.x;
    const int cpx = (gxy * gridDim.z) >> 3;   // 64
    int swz = (bid & 7) * cpx + (bid >> 3);
    const int z  = swz / gxy;
    const int r2 = swz - z * gxy;
    const int by = r2 / gx;
    const int bx = r2 - by * gx;

    const short* __restrict__ A = z ? Ab : Aa;   // batch matrix [M,K]
    const short* __restrict__ B = z ? Bb : Ba;   // weights [N,K]
    unsigned short* __restrict__ C = z ? Cb : Ca;
    const int brow = by * 256, bcol = bx * 256;

    const int t    = threadIdx.x;
    const int lane = t & 63, w = t >> 6;
    const int wr = w >> 2, wc = w & 3;    // wr: gate half (128), wc: batch quarter (64)
    const int lr = lane & 15, kc = lane >> 4;

    // ---- staging addresses ----
    const int ci0 = t, ci1 = t + 512;
    const int r0 = ci0 >> 2, l0 = (ci0 & 3) ^ ((r0 >> 1) & 3);
    const int r1 = ci1 >> 2, l1 = (ci1 & 3) ^ ((r1 >> 1) & 3);
    const int gA0 = (brow + r0) * K + l0 * 8;
    const int gA1 = (brow + r1) * K + l1 * 8;
    const int gB0 = (bcol + r0) * K + l0 * 8;
    const int gB1 = (bcol + r1) * K + l1 * 8;
    const int d0 = ci0 * 8, d1 = ci1 * 8;

#define STAGE_A(u) { const int so_ = ((u) & 3) * 8192; \
    gload_lds16(A + gA0 + (u) * 32, ldsA + so_ + d0);  \
    gload_lds16(A + gA1 + (u) * 32, ldsA + so_ + d1); }
#define STAGE_B(u) { const int so_ = ((u) & 3) * 8192; \
    gload_lds16(B + gB0 + (u) * 32, ldsB + so_ + d0);  \
    gload_lds16(B + gB1 + (u) * 32, ldsB + so_ + d1); }

    // ---- ds_read offsets: W-frags (weights, 8) and X-frags (batch, 4) ----
    int offW[8], offX[4];
#pragma unroll
    for (int f = 0; f < 8; ++f) {
        int r = wr * 128 + f * 16 + lr;
        offW[f] = r * 32 + ((kc ^ ((r >> 1) & 3)) * 8);
    }
#pragma unroll
    for (int n = 0; n < 4; ++n) {
        int r = wc * 64 + n * 16 + lr;
        offX[n] = r * 32 + ((kc ^ ((r >> 1) & 3)) * 8);
    }

    f32x4 acc[8][4];
#pragma unroll
    for (int i = 0; i < 8; ++i)
#pragma unroll
        for (int j = 0; j < 4; ++j)
            acc[i][j] = (f32x4){0.f, 0.f, 0.f, 0.f};

    STAGE_A(0); STAGE_B(0); STAGE_A(1); STAGE_B(1); STAGE_A(2);
    asm volatile("s_waitcnt vmcnt(6)" ::: "memory");
    __builtin_amdgcn_s_barrier();

#pragma unroll 4
    for (int T = 0; T < GNT; ++T) {
        const int so = (T & 3) * 8192;
        bf16x8 w0, w1, w2, w3, x0, x1, x2, x3;

        // ---- phase 0: W-frags 0-3 x all X ----
        w0 = *(const bf16x8*)&ldsB[so + offW[0]];
        w1 = *(const bf16x8*)&ldsB[so + offW[1]];
        w2 = *(const bf16x8*)&ldsB[so + offW[2]];
        w3 = *(const bf16x8*)&ldsB[so + offW[3]];
        x0 = *(const bf16x8*)&ldsA[so + offX[0]];
        x1 = *(const bf16x8*)&ldsA[so + offX[1]];
        x2 = *(const bf16x8*)&ldsA[so + offX[2]];
        x3 = *(const bf16x8*)&ldsA[so + offX[3]];
        if (T + 2 < GNT) STAGE_B(T + 2);
        __builtin_amdgcn_s_barrier();
        asm volatile("s_waitcnt lgkmcnt(0)" ::: "memory");
        __builtin_amdgcn_sched_barrier(0);
        __builtin_amdgcn_s_setprio(1);
        acc[0][0] = __builtin_amdgcn_mfma_f32_16x16x32_bf16(w0, x0, acc[0][0], 0, 0, 0);
        acc[0][1] = __builtin_amdgcn_mfma_f32_16x16x32_bf16(w0, x1, acc[0][1], 0, 0, 0);
        acc[0][2] = __builtin_amdgcn_mfma_f32_16x16x32_bf16(w0, x2, acc[0][2], 0, 0, 0);
        acc[0][3] = __builtin_amdgcn_mfma_f32_16x16x32_bf16(w0, x3, acc[0][3], 0, 0, 0);
        acc[1][0] = __builtin_amdgcn_mfma_f32_16x16x32_bf16(w1, x0, acc[1][0], 0, 0, 0);
        acc[1][1] = __builtin_amdgcn_mfma_f32_16x16x32_bf16(w1, x1, acc[1][1], 0, 0, 0);
        acc[1][2] = __builtin_amdgcn_mfma_f32_16x16x32_bf16(w1, x2, acc[1][2], 0, 0, 0);
        acc[1][3] = __builtin_amdgcn_mfma_f32_16x16x32_bf16(w1, x3, acc[1][3], 0, 0, 0);
        acc[2][0] = __builtin_amdgcn_mfma_f32_16x16x32_bf16(w2, x0, acc[2][0], 0, 0, 0);
        acc[2][1] = __builtin_amdgcn_mfma_f32_16x16x32_bf16(w2, x1, acc[2][1], 0, 0, 0);
        acc[2][2] = __builtin_amdgcn_mfma_f32_16x16x32_bf16(w2, x2, acc[2][2], 0, 0, 0);
        acc[2][3] = __builtin_amdgcn_mfma_f32_16x16x32_bf16(w2, x3, acc[2][3], 0, 0, 0);
        acc[3][0] = __builtin_amdgcn_mfma_f32_16x16x32_bf16(w3, x0, acc[3][0], 0, 0, 0);
        acc[3][1] = __builtin_amdgcn_mfma_f32_16x16x32_bf16(w3, x1, acc[3][1], 0, 0, 0);
        acc[3][2] = __builtin_amdgcn_mfma_f32_16x16x32_bf16(w3, x2, acc[3][2], 0, 0, 0);
        acc[3][3] = __builtin_amdgcn_mfma_f32_16x16x32_bf16(w3, x3, acc[3][3], 0, 0, 0);
        __builtin_amdgcn_s_setprio(0);
        __builtin_amdgcn_s_barrier();

        // ---- phase 1: W-frags 4-7 x all X ----
        w0 = *(const bf16x8*)&ldsB[so + offW[4]];
        w1 = *(const bf16x8*)&ldsB[so + offW[5]];
        w2 = *(const bf16x8*)&ldsB[so + offW[6]];
        w3 = *(const bf16x8*)&ldsB[so + offW[7]];
        if (T + 3 < GNT) STAGE_A(T + 3);
        __builtin_amdgcn_s_barrier();
        asm volatile("s_waitcnt lgkmcnt(0)" ::: "memory");
        __builtin_amdgcn_sched_barrier(0);
        __builtin_amdgcn_s_setprio(1);
        acc[4][0] = __builtin_amdgcn_mfma_f32_16x16x32_bf16(w0, x0, acc[4][0], 0, 0, 0);
        acc[4][1] = __builtin_amdgcn_mfma_f32_16x16x32_bf16(w0, x1, acc[4][1], 0, 0, 0);
        acc[4][2] = __builtin_amdgcn_mfma_f32_16x16x32_bf16(w0, x2, acc[4][2], 0, 0, 0);
        acc[4][3] = __builtin_amdgcn_mfma_f32_16x16x32_bf16(w0, x3, acc[4][3], 0, 0, 0);
        acc[5][0] = __builtin_amdgcn_mfma_f32_16x16x32_bf16(w1, x0, acc[5][0], 0, 0, 0);
        acc[5][1] = __builtin_amdgcn_mfma_f32_16x16x32_bf16(w1, x1, acc[5][1], 0, 0, 0);
        acc[5][2] = __builtin_amdgcn_mfma_f32_16x16x32_bf16(w1, x2, acc[5][2], 0, 0, 0);
        acc[5][3] = __builtin_amdgcn_mfma_f32_16x16x32_bf16(w1, x3, acc[5][3], 0, 0, 0);
        acc[6][0] = __builtin_amdgcn_mfma_f32_16x16x32_bf16(w2, x0, acc[6][0], 0, 0, 0);
        acc[6][1] = __builtin_amdgcn_mfma_f32_16x16x32_bf16(w2, x1, acc[6][1], 0, 0, 0);
        acc[6][2] = __builtin_amdgcn_mfma_f32_16x16x32_bf16(w2, x2, acc[6][2], 0, 0, 0);
        acc[6][3] = __builtin_amdgcn_mfma_f32_16x16x32_bf16(w2, x3, acc[6][3], 0, 0, 0);
        acc[7][0] = __builtin_amdgcn_mfma_f32_16x16x32_bf16(w3, x0, acc[7][0], 0, 0, 0);
        acc[7][1] = __builtin_amdgcn_mfma_f32_16x16x32_bf16(w3, x1, acc[7][1], 0, 0, 0);
        acc[7][2] = __builtin_amdgcn_mfma_f32_16x16x32_bf16(w3, x2, acc[7][2], 0, 0, 0);
        acc[7][3] = __builtin_amdgcn_mfma_f32_16x16x32_bf16(w3, x3, acc[7][3], 0, 0, 0);
        __builtin_amdgcn_s_setprio(0);
        if (T < GNT - 3)      { asm volatile("s_waitcnt vmcnt(6)" ::: "memory"); }
        else if (T == GNT - 3){ asm volatile("s_waitcnt vmcnt(4)" ::: "memory"); }
        else if (T == GNT - 2){ asm volatile("s_waitcnt vmcnt(0)" ::: "memory"); }
        __builtin_amdgcn_s_barrier();
    }

    // ---- epilogue ----
    // lane holds: gate cols gc0+f*16 .. +3 (reg dim), batch row mrow0+n*16
    const int gc0   = bcol + wr * 128 + kc * 4;
    const int mrow0 = brow + wc * 64 + lr;

    float4 bias4[8];
#pragma unroll
    for (int f = 0; f < 8; ++f) {
        if (z) bias4[f] = *reinterpret_cast<const float4*>(&Bias[gc0 + f * 16]);
        else   bias4[f] = (float4){0.f, 0.f, 0.f, 0.f};
    }

    float s[4] = {0.f, 0.f, 0.f, 0.f}, q[4] = {0.f, 0.f, 0.f, 0.f};
#pragma unroll
    for (int f = 0; f < 8; ++f) {
#pragma unroll
        for (int n = 0; n < 4; ++n) {
            float v0 = acc[f][n][0] + bias4[f].x;
            float v1 = acc[f][n][1] + bias4[f].y;
            float v2 = acc[f][n][2] + bias4[f].z;
            float v3 = acc[f][n][3] + bias4[f].w;
            unsigned u0 = f2bf(v0), u1 = f2bf(v1), u2 = f2bf(v2), u3 = f2bf(v3);
            float e0 = bf2f(u0), e1 = bf2f(u1), e2 = bf2f(u2), e3 = bf2f(u3);
            s[n] += (e0 + e1) + (e2 + e3);
            q[n] += (e0 * e0 + e1 * e1) + (e2 * e2 + e3 * e3);
            uint2 pk; pk.x = u0 | (u1 << 16); pk.y = u2 | (u3 << 16);
            *reinterpret_cast<uint2*>(&C[(size_t)(mrow0 + n * 16) * N + gc0 + f * 16]) = pk;
        }
    }
    // reduce over kc groups (lanes ^16, ^32): full 256-col partial per batch row
#pragma unroll
    for (int n = 0; n < 4; ++n) {
        s[n] += __shfl_xor(s[n], 16); s[n] += __shfl_xor(s[n], 32);
        q[n] += __shfl_xor(q[n], 16); q[n] += __shfl_xor(q[n], 32);
    }

    __syncthreads();                       // done with tile LDS
    float2* part = (float2*)lds;           // [2 (wr)][256 rows]
    if (kc == 0) {
#pragma unroll
        for (int n = 0; n < 4; ++n) {
            float2 pr; pr.x = s[n]; pr.y = q[n];
            part[wr * 256 + wc * 64 + n * 16 + lr] = pr;
        }
    }
    __syncthreads();
    if (t < 256) {
        float2 p0 = part[t], p1 = part[256 + t];
        float2 o; o.x = p0.x + p1.x; o.y = p0.y + p1.y;
        P[((size_t)(z * 16 + by) * 256 + t) * 16 + bx] = o;
    }
#undef STAGE_A
#undef STAGE_B
}

// ---------------- fold 16 col-block partials -> (mean, rstd) per row ----------------
__global__ __launch_bounds__(256) void reduce_stats(const float2* __restrict__ P,
                                                    float2* __restrict__ stats, float invn) {
    const int row = blockIdx.x * 256 + threadIdx.x;   // 0..8191
    float s = 0.f, q = 0.f;
#pragma unroll
    for (int b = 0; b < 16; ++b) { float2 v = P[(size_t)row * 16 + b]; s += v.x; q += v.y; }
    float m = s * invn;
    float r = rsqrtf(q * invn - m * m + LN_EPS);
    float2 o; o.x = m; o.y = r;
    stats[row] = o;
}

// ---------------- single-pass LN + LSTM pointwise ----------------
__global__ __launch_bounds__(256) void ln_lstm(
    const unsigned short* __restrict__ i2h,   // [B,4H] bf16 (rounded)
    const unsigned short* __restrict__ h2h,   // [B,4H] bf16 (bias included)
    const float* __restrict__ cx,
    const float2* __restrict__ statsI, const float2* __restrict__ statsH,
    const float* __restrict__ g_ih, const float* __restrict__ be_ih,
    const float* __restrict__ g_hh, const float* __restrict__ be_hh,
    const float* __restrict__ g_ho, const float* __restrict__ be_ho,
    float* __restrict__ hy, float* __restrict__ cy, int H)
{
    const int b = blockIdx.x;
    const int t = threadIdx.x;
    const int lane = t & 63;
    const int wave = t >> 6;
    const int H4 = 4 * H;
    const int h0 = t * 4;

    const unsigned short* xi = i2h + (size_t)b * H4;
    const unsigned short* xh = h2h + (size_t)b * H4;

    const float2 sI = statsI[b];
    const float2 sH = statsH[b];

    __shared__ float red[4][2];

    float gate[4][4];
#pragma unroll
    for (int q = 0; q < 4; ++q) {
        const int j = q * H + h0;
        ushort4 vi = *reinterpret_cast<const ushort4*>(&xi[j]);
        ushort4 vh = *reinterpret_cast<const ushort4*>(&xh[j]);
        float4 gi = *reinterpret_cast<const float4*>(&g_ih[j]);
        float4 bi = *reinterpret_cast<const float4*>(&be_ih[j]);
        float4 gh = *reinterpret_cast<const float4*>(&g_hh[j]);
        float4 bh = *reinterpret_cast<const float4*>(&be_hh[j]);
        gate[q][0] = (bf2f(vi.x) - sI.x) * sI.y * gi.x + bi.x + (bf2f(vh.x) - sH.x) * sH.y * gh.x + bh.x;
        gate[q][1] = (bf2f(vi.y) - sI.x) * sI.y * gi.y + bi.y + (bf2f(vh.y) - sH.x) * sH.y * gh.y + bh.y;
        gate[q][2] = (bf2f(vi.z) - sI.x) * sI.y * gi.z + bi.z + (bf2f(vh.z) - sH.x) * sH.y * gh.z + bh.z;
        gate[q][3] = (bf2f(vi.w) - sI.x) * sI.y * gi.w + bi.w + (bf2f(vh.w) - sH.x) * sH.y * gh.w + bh.w;
    }

    float4 cxv = *reinterpret_cast<const float4*>(&cx[(size_t)b * H + h0]);
    float cvals[4] = {cxv.x, cxv.y, cxv.z, cxv.w};
    float tv[4], ov[4];
    float s2 = 0.f, q2 = 0.f;
    float4 cyv;
#pragma unroll
    for (int k = 0; k < 4; ++k) {
        float c = sigf(gate[1][k]) * cvals[k] + sigf(gate[0][k]) * tanh_fast(gate[3][k]);
        ((float*)&cyv)[k] = c;
        float tc = tanh_fast(c);
        tv[k] = tc; ov[k] = sigf(gate[2][k]);
        s2 += tc; q2 += tc * tc;
    }
    *reinterpret_cast<float4*>(&cy[(size_t)b * H + h0]) = cyv;

    s2 = wred(s2); q2 = wred(q2);
    if (lane == 0) { red[wave][0] = s2; red[wave][1] = q2; }
    __syncthreads();
    float S2 = red[0][0] + red[1][0] + red[2][0] + red[3][0];
    float Q2 = red[0][1] + red[1][1] + red[2][1] + red[3][1];
    const float invH = 1.0f / (float)H;
    float mt = S2 * invH;
    float rt = rsqrtf(Q2 * invH - mt * mt + LN_EPS);

    float4 go = *reinterpret_cast<const float4*>(&g_ho[h0]);
    float4 bo = *reinterpret_cast<const float4*>(&be_ho[h0]);
    float4 hyv;
    hyv.x = ov[0] * ((tv[0] - mt) * rt * go.x + bo.x);
    hyv.y = ov[1] * ((tv[1] - mt) * rt * go.y + bo.y);
    hyv.z = ov[2] * ((tv[2] - mt) * rt * go.z + bo.z);
    hyv.w = ov[3] * ((tv[3] - mt) * rt * go.w + bo.w);
    *reinterpret_cast<float4*>(&hy[(size_t)b * H + h0]) = hyv;
}

// ---------------- launcher ----------------
extern "C" void kernel_launch(void* const* d_in, const int* in_sizes, int n_in,
                              void* d_out, int out_size, void* d_ws, size_t ws_size,
                              hipStream_t stream) {
    const float* inputs  = (const float*)d_in[0];
    const float* hx      = (const float*)d_in[1];
    const float* cx      = (const float*)d_in[2];
    const float* w_ih    = (const float*)d_in[3];
    const float* w_hh    = (const float*)d_in[4];
    const float* b_hh    = (const float*)d_in[5];
    const float* g_ih    = (const float*)d_in[6];
    const float* beta_ih = (const float*)d_in[7];
    const float* g_hh    = (const float*)d_in[8];
    const float* beta_hh = (const float*)d_in[9];
    const float* g_ho    = (const float*)d_in[10];
    const float* beta_ho = (const float*)d_in[11];

    const int H  = in_sizes[10];            // 1024
    const int B  = in_sizes[1] / H;         // 4096
    const int D  = in_sizes[0] / B;         // 1024
    const int H4 = 4 * H;

    uint8_t* ws = (uint8_t*)d_ws;
    size_t off = 0;
    short* Abf  = (short*)(ws + off); off += (size_t)B * D * 2;
    short* Hbf  = (short*)(ws + off); off += (size_t)B * H * 2;
    short* Wih  = (short*)(ws + off); off += (size_t)H4 * D * 2;
    short* Whh  = (short*)(ws + off); off += (size_t)H4 * H * 2;
    unsigned short* i2hb = (unsigned short*)(ws + off); off += (size_t)B * H4 * 2;
    unsigned short* h2hb = (unsigned short*)(ws + off); off += (size_t)B * H4 * 2;
    float2* P     = (float2*)(ws + off); off += (size_t)2 * 16 * 256 * 16 * sizeof(float2);
    float2* stats = (float2*)(ws + off); off += (size_t)2 * B * sizeof(float2);

    float* hy  = (float*)d_out;
    float* cyo = (float*)d_out + (size_t)B * H;

    // 1) all casts in one launch
    {
        const int n0 = (B * D) / 4, n1 = (B * H) / 4, n2 = (H4 * D) / 4, n3 = (H4 * H) / 4;
        const int tot = n0 + n1 + n2 + n3;
        cast_all<<<(tot + 255) / 256, 256, 0, stream>>>(
            (const float4*)inputs, (ushort4*)Abf, n0,
            (const float4*)hx,     (ushort4*)Hbf, n1,
            (const float4*)w_ih,   (ushort4*)Wih, n2,
            (const float4*)w_hh,   (ushort4*)Whh, n3);
    }

    // 2) both GEMMs + fused LN-stats partials
    {
        dim3 grid(H4 / 256, B / 256, 2);
        gemm8p<<<grid, 512, 0, stream>>>(Abf, Wih, i2hb, Hbf, Whh, h2hb, b_hh, P, H4, D);
    }

    // 3) fold partials -> (mean, rstd) per row, both matrices
    reduce_stats<<<(2 * B) / 256, 256, 0, stream>>>(P, stats, 1.0f / (float)H4);

    // 4) single-pass LN + LSTM
    ln_lstm<<<B, 256, 0, stream>>>(i2hb, h2hb, cx, stats, stats + B,
                                   g_ih, beta_ih, g_hh, beta_hh, g_ho, beta_ho,
                                   hy, cyo, H);
}

// Round 5
// 126.452 us; speedup vs baseline: 1.4704x; 1.0106x over previous
//
#include <hip/hip_runtime.h>
#include <hip/hip_bf16.h>
#include <stdint.h>

typedef __attribute__((ext_vector_type(8))) short bf16x8;
typedef __attribute__((ext_vector_type(4))) float f32x4;

#define LN_EPS 1e-5f

// ---------------- helpers ----------------
__device__ inline unsigned f2bf(float f) {
    unsigned u = __builtin_bit_cast(unsigned, f);
    u += 0x7fffu + ((u >> 16) & 1u);          // RNE
    return u >> 16;
}
__device__ inline float bf2f(unsigned u) {
    return __builtin_bit_cast(float, u << 16);
}
__device__ inline float sigf(float x) {
    return 1.0f / (1.0f + __expf(-x));
}
__device__ inline float tanh_fast(float x) {
    return __builtin_fmaf(2.0f, 1.0f / (1.0f + __expf(-2.0f * x)), -1.0f);
}
__device__ inline float wred(float v) {
#pragma unroll
    for (int o = 32; o > 0; o >>= 1) v += __shfl_xor(v, o);
    return v;
}
__device__ inline void gload_lds16(const void* g, void* l) {
    __builtin_amdgcn_global_load_lds(
        (const __attribute__((address_space(1))) void*)g,
        (__attribute__((address_space(3))) void*)l, 16, 0, 0);
}

// ---------------- merged cast f32 -> bf16 (4 regions, 1 launch) ----------------
__global__ __launch_bounds__(256) void cast_all(
    const float4* __restrict__ s0, ushort4* __restrict__ d0, int n0,
    const float4* __restrict__ s1, ushort4* __restrict__ d1, int n1,
    const float4* __restrict__ s2, ushort4* __restrict__ d2, int n2,
    const float4* __restrict__ s3, ushort4* __restrict__ d3, int n3)
{
    int j = blockIdx.x * blockDim.x + threadIdx.x;
    const float4* s; ushort4* d;
    if (j < n0) { s = s0; d = d0; }
    else {
        j -= n0;
        if (j < n1) { s = s1; d = d1; }
        else {
            j -= n1;
            if (j < n2) { s = s2; d = d2; }
            else {
                j -= n2;
                if (j >= n3) return;
                s = s3; d = d3;
            }
        }
    }
    float4 v = s[j];
    ushort4 o;
    o.x = (unsigned short)f2bf(v.x); o.y = (unsigned short)f2bf(v.y);
    o.z = (unsigned short)f2bf(v.z); o.w = (unsigned short)f2bf(v.w);
    d[j] = o;
}

// =====================================================================
// 256x256 bf16 NT GEMM, pipelined (ring-4 LDS, counted vmcnt, setprio,
// XOR chunk swizzle, bijective XCD swizzle). Swapped-operand MFMA:
// acc[f][n] = mfma(W_frag[f], X_frag[n]) -> lane holds 4 consecutive gate
// cols at one batch row. Epilogue: +bias (z=1), bf16 pack + in-lane LN
// stats, LDS-transpose for fully coalesced dwordx4 C stores.
// =====================================================================
#define GNT 32   // K/32

__global__ __launch_bounds__(512) void gemm8p(
    const short* __restrict__ Aa, const short* __restrict__ Ba, unsigned short* __restrict__ Ca,
    const short* __restrict__ Ab, const short* __restrict__ Bb, unsigned short* __restrict__ Cb,
    const float* __restrict__ Bias,   // b_hh, used when z==1
    float2* __restrict__ P,           // [2][16][256][16] per-row partial stats
    int N, int K)
{
    __shared__ __attribute__((aligned(16))) short lds[65536];  // 128 KiB
    short* ldsA = lds;            // batch tile: 4 slots x (256 rows x 32 k)
    short* ldsB = lds + 32768;    // weight tile: 4 slots

    // ---- T1: bijective XCD swizzle over 512 blocks ----
    const int gx  = gridDim.x;            // 16
    const int gxy = gx * gridDim.y;       // 256
    int bid = (blockIdx.z * gridDim.y + blockIdx.y) * gx + blockIdx.x;
    const int cpx = (gxy * gridDim.z) >> 3;   // 64
    int swz = (bid & 7) * cpx + (bid >> 3);
    const int z  = swz / gxy;
    const int r2 = swz - z * gxy;
    const int by = r2 / gx;
    const int bx = r2 - by * gx;

    const short* __restrict__ A = z ? Ab : Aa;   // batch matrix [M,K]
    const short* __restrict__ B = z ? Bb : Ba;   // weights [N,K]
    unsigned short* __restrict__ C = z ? Cb : Ca;
    const int brow = by * 256, bcol = bx * 256;

    const int t    = threadIdx.x;
    const int lane = t & 63, w = t >> 6;
    const int wr = w >> 2, wc = w & 3;    // wr: gate half (128), wc: batch quarter (64)
    const int lr = lane & 15, kc = lane >> 4;

    // ---- staging addresses ----
    const int ci0 = t, ci1 = t + 512;
    const int r0 = ci0 >> 2, l0 = (ci0 & 3) ^ ((r0 >> 1) & 3);
    const int r1 = ci1 >> 2, l1 = (ci1 & 3) ^ ((r1 >> 1) & 3);
    const int gA0 = (brow + r0) * K + l0 * 8;
    const int gA1 = (brow + r1) * K + l1 * 8;
    const int gB0 = (bcol + r0) * K + l0 * 8;
    const int gB1 = (bcol + r1) * K + l1 * 8;
    const int d0 = ci0 * 8, d1 = ci1 * 8;

#define STAGE_A(u) { const int so_ = ((u) & 3) * 8192; \
    gload_lds16(A + gA0 + (u) * 32, ldsA + so_ + d0);  \
    gload_lds16(A + gA1 + (u) * 32, ldsA + so_ + d1); }
#define STAGE_B(u) { const int so_ = ((u) & 3) * 8192; \
    gload_lds16(B + gB0 + (u) * 32, ldsB + so_ + d0);  \
    gload_lds16(B + gB1 + (u) * 32, ldsB + so_ + d1); }

    // ---- ds_read offsets: W-frags (weights, 8) and X-frags (batch, 4) ----
    int offW[8], offX[4];
#pragma unroll
    for (int f = 0; f < 8; ++f) {
        int r = wr * 128 + f * 16 + lr;
        offW[f] = r * 32 + ((kc ^ ((r >> 1) & 3)) * 8);
    }
#pragma unroll
    for (int n = 0; n < 4; ++n) {
        int r = wc * 64 + n * 16 + lr;
        offX[n] = r * 32 + ((kc ^ ((r >> 1) & 3)) * 8);
    }

    f32x4 acc[8][4];
#pragma unroll
    for (int i = 0; i < 8; ++i)
#pragma unroll
        for (int j = 0; j < 4; ++j)
            acc[i][j] = (f32x4){0.f, 0.f, 0.f, 0.f};

    STAGE_A(0); STAGE_B(0); STAGE_A(1); STAGE_B(1); STAGE_A(2);
    asm volatile("s_waitcnt vmcnt(6)" ::: "memory");
    __builtin_amdgcn_s_barrier();

#pragma unroll 4
    for (int T = 0; T < GNT; ++T) {
        const int so = (T & 3) * 8192;
        bf16x8 w0, w1, w2, w3, x0, x1, x2, x3;

        // ---- phase 0: W-frags 0-3 x all X ----
        w0 = *(const bf16x8*)&ldsB[so + offW[0]];
        w1 = *(const bf16x8*)&ldsB[so + offW[1]];
        w2 = *(const bf16x8*)&ldsB[so + offW[2]];
        w3 = *(const bf16x8*)&ldsB[so + offW[3]];
        x0 = *(const bf16x8*)&ldsA[so + offX[0]];
        x1 = *(const bf16x8*)&ldsA[so + offX[1]];
        x2 = *(const bf16x8*)&ldsA[so + offX[2]];
        x3 = *(const bf16x8*)&ldsA[so + offX[3]];
        if (T + 2 < GNT) STAGE_B(T + 2);
        __builtin_amdgcn_s_barrier();
        asm volatile("s_waitcnt lgkmcnt(0)" ::: "memory");
        __builtin_amdgcn_sched_barrier(0);
        __builtin_amdgcn_s_setprio(1);
        acc[0][0] = __builtin_amdgcn_mfma_f32_16x16x32_bf16(w0, x0, acc[0][0], 0, 0, 0);
        acc[0][1] = __builtin_amdgcn_mfma_f32_16x16x32_bf16(w0, x1, acc[0][1], 0, 0, 0);
        acc[0][2] = __builtin_amdgcn_mfma_f32_16x16x32_bf16(w0, x2, acc[0][2], 0, 0, 0);
        acc[0][3] = __builtin_amdgcn_mfma_f32_16x16x32_bf16(w0, x3, acc[0][3], 0, 0, 0);
        acc[1][0] = __builtin_amdgcn_mfma_f32_16x16x32_bf16(w1, x0, acc[1][0], 0, 0, 0);
        acc[1][1] = __builtin_amdgcn_mfma_f32_16x16x32_bf16(w1, x1, acc[1][1], 0, 0, 0);
        acc[1][2] = __builtin_amdgcn_mfma_f32_16x16x32_bf16(w1, x2, acc[1][2], 0, 0, 0);
        acc[1][3] = __builtin_amdgcn_mfma_f32_16x16x32_bf16(w1, x3, acc[1][3], 0, 0, 0);
        acc[2][0] = __builtin_amdgcn_mfma_f32_16x16x32_bf16(w2, x0, acc[2][0], 0, 0, 0);
        acc[2][1] = __builtin_amdgcn_mfma_f32_16x16x32_bf16(w2, x1, acc[2][1], 0, 0, 0);
        acc[2][2] = __builtin_amdgcn_mfma_f32_16x16x32_bf16(w2, x2, acc[2][2], 0, 0, 0);
        acc[2][3] = __builtin_amdgcn_mfma_f32_16x16x32_bf16(w2, x3, acc[2][3], 0, 0, 0);
        acc[3][0] = __builtin_amdgcn_mfma_f32_16x16x32_bf16(w3, x0, acc[3][0], 0, 0, 0);
        acc[3][1] = __builtin_amdgcn_mfma_f32_16x16x32_bf16(w3, x1, acc[3][1], 0, 0, 0);
        acc[3][2] = __builtin_amdgcn_mfma_f32_16x16x32_bf16(w3, x2, acc[3][2], 0, 0, 0);
        acc[3][3] = __builtin_amdgcn_mfma_f32_16x16x32_bf16(w3, x3, acc[3][3], 0, 0, 0);
        __builtin_amdgcn_s_setprio(0);
        __builtin_amdgcn_s_barrier();

        // ---- phase 1: W-frags 4-7 x all X ----
        w0 = *(const bf16x8*)&ldsB[so + offW[4]];
        w1 = *(const bf16x8*)&ldsB[so + offW[5]];
        w2 = *(const bf16x8*)&ldsB[so + offW[6]];
        w3 = *(const bf16x8*)&ldsB[so + offW[7]];
        if (T + 3 < GNT) STAGE_A(T + 3);
        __builtin_amdgcn_s_barrier();
        asm volatile("s_waitcnt lgkmcnt(0)" ::: "memory");
        __builtin_amdgcn_sched_barrier(0);
        __builtin_amdgcn_s_setprio(1);
        acc[4][0] = __builtin_amdgcn_mfma_f32_16x16x32_bf16(w0, x0, acc[4][0], 0, 0, 0);
        acc[4][1] = __builtin_amdgcn_mfma_f32_16x16x32_bf16(w0, x1, acc[4][1], 0, 0, 0);
        acc[4][2] = __builtin_amdgcn_mfma_f32_16x16x32_bf16(w0, x2, acc[4][2], 0, 0, 0);
        acc[4][3] = __builtin_amdgcn_mfma_f32_16x16x32_bf16(w0, x3, acc[4][3], 0, 0, 0);
        acc[5][0] = __builtin_amdgcn_mfma_f32_16x16x32_bf16(w1, x0, acc[5][0], 0, 0, 0);
        acc[5][1] = __builtin_amdgcn_mfma_f32_16x16x32_bf16(w1, x1, acc[5][1], 0, 0, 0);
        acc[5][2] = __builtin_amdgcn_mfma_f32_16x16x32_bf16(w1, x2, acc[5][2], 0, 0, 0);
        acc[5][3] = __builtin_amdgcn_mfma_f32_16x16x32_bf16(w1, x3, acc[5][3], 0, 0, 0);
        acc[6][0] = __builtin_amdgcn_mfma_f32_16x16x32_bf16(w2, x0, acc[6][0], 0, 0, 0);
        acc[6][1] = __builtin_amdgcn_mfma_f32_16x16x32_bf16(w2, x1, acc[6][1], 0, 0, 0);
        acc[6][2] = __builtin_amdgcn_mfma_f32_16x16x32_bf16(w2, x2, acc[6][2], 0, 0, 0);
        acc[6][3] = __builtin_amdgcn_mfma_f32_16x16x32_bf16(w2, x3, acc[6][3], 0, 0, 0);
        acc[7][0] = __builtin_amdgcn_mfma_f32_16x16x32_bf16(w3, x0, acc[7][0], 0, 0, 0);
        acc[7][1] = __builtin_amdgcn_mfma_f32_16x16x32_bf16(w3, x1, acc[7][1], 0, 0, 0);
        acc[7][2] = __builtin_amdgcn_mfma_f32_16x16x32_bf16(w3, x2, acc[7][2], 0, 0, 0);
        acc[7][3] = __builtin_amdgcn_mfma_f32_16x16x32_bf16(w3, x3, acc[7][3], 0, 0, 0);
        __builtin_amdgcn_s_setprio(0);
        if (T < GNT - 3)      { asm volatile("s_waitcnt vmcnt(6)" ::: "memory"); }
        else if (T == GNT - 3){ asm volatile("s_waitcnt vmcnt(4)" ::: "memory"); }
        else if (T == GNT - 2){ asm volatile("s_waitcnt vmcnt(0)" ::: "memory"); }
        __builtin_amdgcn_s_barrier();
    }

    // ---- epilogue: bias, pack to bf16, in-lane stats ----
    float4 bias4[8];
#pragma unroll
    for (int f = 0; f < 8; ++f) {
        if (z) bias4[f] = *reinterpret_cast<const float4*>(&Bias[bcol + wr * 128 + f * 16 + kc * 4]);
        else   bias4[f] = (float4){0.f, 0.f, 0.f, 0.f};
    }

    uint2 pk[8][4];
    float s[4] = {0.f, 0.f, 0.f, 0.f}, q[4] = {0.f, 0.f, 0.f, 0.f};
#pragma unroll
    for (int f = 0; f < 8; ++f) {
#pragma unroll
        for (int n = 0; n < 4; ++n) {
            float v0 = acc[f][n][0] + bias4[f].x;
            float v1 = acc[f][n][1] + bias4[f].y;
            float v2 = acc[f][n][2] + bias4[f].z;
            float v3 = acc[f][n][3] + bias4[f].w;
            unsigned u0 = f2bf(v0), u1 = f2bf(v1), u2 = f2bf(v2), u3 = f2bf(v3);
            float e0 = bf2f(u0), e1 = bf2f(u1), e2 = bf2f(u2), e3 = bf2f(u3);
            s[n] += (e0 + e1) + (e2 + e3);
            q[n] += (e0 * e0 + e1 * e1) + (e2 * e2 + e3 * e3);
            pk[f][n].x = u0 | (u1 << 16);
            pk[f][n].y = u2 | (u3 << 16);
        }
    }
#pragma unroll
    for (int n = 0; n < 4; ++n) {
        s[n] += __shfl_xor(s[n], 16); s[n] += __shfl_xor(s[n], 32);
        q[n] += __shfl_xor(q[n], 16); q[n] += __shfl_xor(q[n], 32);
    }

    // ---- stats partials -> P (reuse first 4 KB of LDS) ----
    __syncthreads();
    float2* part = (float2*)lds;           // [2 (wr)][256 rows]
    if (kc == 0) {
#pragma unroll
        for (int n = 0; n < 4; ++n) {
            float2 pr; pr.x = s[n]; pr.y = q[n];
            part[wr * 256 + wc * 64 + n * 16 + lr] = pr;
        }
    }
    __syncthreads();
    if (t < 256) {
        float2 p0 = part[t], p1 = part[256 + t];
        float2 o; o.x = p0.x + p1.x; o.y = p0.y + p1.y;
        P[((size_t)(z * 16 + by) * 256 + t) * 16 + bx] = o;
    }
    __syncthreads();

    // ---- LDS transpose: swizzled b64 writes, then coalesced dwordx4 stores ----
    uint8_t* cb = (uint8_t*)lds;           // 256 rows x 512 B = 128 KiB exactly
    const int rloc0 = wc * 64 + lr;
#pragma unroll
    for (int f = 0; f < 8; ++f) {
        const int colB = wr * 256 + f * 32 + kc * 8;
#pragma unroll
        for (int n = 0; n < 4; ++n) {
            const int r = rloc0 + n * 16;
            *reinterpret_cast<uint2*>(cb + r * 512 + (colB ^ ((r & 7) << 4))) = pk[f][n];
        }
    }
    __syncthreads();
    {
        const int rr = t >> 5;             // 0..15
        const int cB = (t & 31) * 16;      // 0..496
#pragma unroll
        for (int i = 0; i < 16; ++i) {
            const int r = rr + i * 16;
            uint4 v = *reinterpret_cast<const uint4*>(cb + r * 512 + (cB ^ ((r & 7) << 4)));
            *reinterpret_cast<uint4*>((uint8_t*)&C[(size_t)(brow + r) * N + bcol] + cB) = v;
        }
    }
#undef STAGE_A
#undef STAGE_B
}

// ---------------- single-pass LN + LSTM pointwise (stats folded in) ----------------
__global__ __launch_bounds__(256) void ln_lstm(
    const unsigned short* __restrict__ i2h,   // [B,4H] bf16 (rounded)
    const unsigned short* __restrict__ h2h,   // [B,4H] bf16 (bias included)
    const float* __restrict__ cx,
    const float2* __restrict__ P,             // [2*B][16] partial (sum,sumsq)
    const float* __restrict__ g_ih, const float* __restrict__ be_ih,
    const float* __restrict__ g_hh, const float* __restrict__ be_hh,
    const float* __restrict__ g_ho, const float* __restrict__ be_ho,
    float* __restrict__ hy, float* __restrict__ cy, int H, int B)
{
    const int b = blockIdx.x;
    const int t = threadIdx.x;
    const int lane = t & 63;
    const int wave = t >> 6;
    const int H4 = 4 * H;
    const int h0 = t * 4;

    const unsigned short* xi = i2h + (size_t)b * H4;
    const unsigned short* xh = h2h + (size_t)b * H4;

    __shared__ float red[4][2];
    __shared__ float st[4];   // mI, rI, mH, rH

    // fold the 16 col-block partials for this row (both matrices) in wave 0
    if (wave == 0) {
        const int half = (lane >> 4) & 1;          // 0: i2h, 1: h2h
        float2 v = (float2){0.f, 0.f};
        if (lane < 32) v = P[((size_t)(half * B + b)) * 16 + (lane & 15)];
        v.x += __shfl_xor(v.x, 1); v.y += __shfl_xor(v.y, 1);
        v.x += __shfl_xor(v.x, 2); v.y += __shfl_xor(v.y, 2);
        v.x += __shfl_xor(v.x, 4); v.y += __shfl_xor(v.y, 4);
        v.x += __shfl_xor(v.x, 8); v.y += __shfl_xor(v.y, 8);
        if (lane < 32 && (lane & 15) == 0) {
            const float inv4H = 1.0f / (float)H4;
            float m = v.x * inv4H;
            float r = rsqrtf(v.y * inv4H - m * m + LN_EPS);
            st[half * 2]     = m;
            st[half * 2 + 1] = r;
        }
    }
    __syncthreads();
    const float mI = st[0], rI = st[1], mH = st[2], rH = st[3];

    float gate[4][4];
#pragma unroll
    for (int q = 0; q < 4; ++q) {
        const int j = q * H + h0;
        ushort4 vi = *reinterpret_cast<const ushort4*>(&xi[j]);
        ushort4 vh = *reinterpret_cast<const ushort4*>(&xh[j]);
        float4 gi = *reinterpret_cast<const float4*>(&g_ih[j]);
        float4 bi = *reinterpret_cast<const float4*>(&be_ih[j]);
        float4 gh = *reinterpret_cast<const float4*>(&g_hh[j]);
        float4 bh = *reinterpret_cast<const float4*>(&be_hh[j]);
        gate[q][0] = (bf2f(vi.x) - mI) * rI * gi.x + bi.x + (bf2f(vh.x) - mH) * rH * gh.x + bh.x;
        gate[q][1] = (bf2f(vi.y) - mI) * rI * gi.y + bi.y + (bf2f(vh.y) - mH) * rH * gh.y + bh.y;
        gate[q][2] = (bf2f(vi.z) - mI) * rI * gi.z + bi.z + (bf2f(vh.z) - mH) * rH * gh.z + bh.z;
        gate[q][3] = (bf2f(vi.w) - mI) * rI * gi.w + bi.w + (bf2f(vh.w) - mH) * rH * gh.w + bh.w;
    }

    float4 cxv = *reinterpret_cast<const float4*>(&cx[(size_t)b * H + h0]);
    float cvals[4] = {cxv.x, cxv.y, cxv.z, cxv.w};
    float tv[4], ov[4];
    float s2 = 0.f, q2 = 0.f;
    float4 cyv;
#pragma unroll
    for (int k = 0; k < 4; ++k) {
        float c = sigf(gate[1][k]) * cvals[k] + sigf(gate[0][k]) * tanh_fast(gate[3][k]);
        ((float*)&cyv)[k] = c;
        float tc = tanh_fast(c);
        tv[k] = tc; ov[k] = sigf(gate[2][k]);
        s2 += tc; q2 += tc * tc;
    }
    *reinterpret_cast<float4*>(&cy[(size_t)b * H + h0]) = cyv;

    s2 = wred(s2); q2 = wred(q2);
    if (lane == 0) { red[wave][0] = s2; red[wave][1] = q2; }
    __syncthreads();
    float S2 = red[0][0] + red[1][0] + red[2][0] + red[3][0];
    float Q2 = red[0][1] + red[1][1] + red[2][1] + red[3][1];
    const float invH = 1.0f / (float)H;
    float mt = S2 * invH;
    float rt = rsqrtf(Q2 * invH - mt * mt + LN_EPS);

    float4 go = *reinterpret_cast<const float4*>(&g_ho[h0]);
    float4 bo = *reinterpret_cast<const float4*>(&be_ho[h0]);
    float4 hyv;
    hyv.x = ov[0] * ((tv[0] - mt) * rt * go.x + bo.x);
    hyv.y = ov[1] * ((tv[1] - mt) * rt * go.y + bo.y);
    hyv.z = ov[2] * ((tv[2] - mt) * rt * go.z + bo.z);
    hyv.w = ov[3] * ((tv[3] - mt) * rt * go.w + bo.w);
    *reinterpret_cast<float4*>(&hy[(size_t)b * H + h0]) = hyv;
}

// ---------------- launcher ----------------
extern "C" void kernel_launch(void* const* d_in, const int* in_sizes, int n_in,
                              void* d_out, int out_size, void* d_ws, size_t ws_size,
                              hipStream_t stream) {
    const float* inputs  = (const float*)d_in[0];
    const float* hx      = (const float*)d_in[1];
    const float* cx      = (const float*)d_in[2];
    const float* w_ih    = (const float*)d_in[3];
    const float* w_hh    = (const float*)d_in[4];
    const float* b_hh    = (const float*)d_in[5];
    const float* g_ih    = (const float*)d_in[6];
    const float* beta_ih = (const float*)d_in[7];
    const float* g_hh    = (const float*)d_in[8];
    const float* beta_hh = (const float*)d_in[9];
    const float* g_ho    = (const float*)d_in[10];
    const float* beta_ho = (const float*)d_in[11];

    const int H  = in_sizes[10];            // 1024
    const int B  = in_sizes[1] / H;         // 4096
    const int D  = in_sizes[0] / B;         // 1024
    const int H4 = 4 * H;

    uint8_t* ws = (uint8_t*)d_ws;
    size_t off = 0;
    short* Abf  = (short*)(ws + off); off += (size_t)B * D * 2;
    short* Hbf  = (short*)(ws + off); off += (size_t)B * H * 2;
    short* Wih  = (short*)(ws + off); off += (size_t)H4 * D * 2;
    short* Whh  = (short*)(ws + off); off += (size_t)H4 * H * 2;
    unsigned short* i2hb = (unsigned short*)(ws + off); off += (size_t)B * H4 * 2;
    unsigned short* h2hb = (unsigned short*)(ws + off); off += (size_t)B * H4 * 2;
    float2* P   = (float2*)(ws + off); off += (size_t)2 * B * 16 * sizeof(float2);

    float* hy  = (float*)d_out;
    float* cyo = (float*)d_out + (size_t)B * H;

    // 1) all casts in one launch
    {
        const int n0 = (B * D) / 4, n1 = (B * H) / 4, n2 = (H4 * D) / 4, n3 = (H4 * H) / 4;
        const int tot = n0 + n1 + n2 + n3;
        cast_all<<<(tot + 255) / 256, 256, 0, stream>>>(
            (const float4*)inputs, (ushort4*)Abf, n0,
            (const float4*)hx,     (ushort4*)Hbf, n1,
            (const float4*)w_ih,   (ushort4*)Wih, n2,
            (const float4*)w_hh,   (ushort4*)Whh, n3);
    }

    // 2) both GEMMs + fused LN-stats partials
    {
        dim3 grid(H4 / 256, B / 256, 2);
        gemm8p<<<grid, 512, 0, stream>>>(Abf, Wih, i2hb, Hbf, Whh, h2hb, b_hh, P, H4, D);
    }

    // 3) single-pass LN + LSTM (folds partials itself)
    ln_lstm<<<B, 256, 0, stream>>>(i2hb, h2hb, cx, P,
                                   g_ih, beta_ih, g_hh, beta_hh, g_ho, beta_ho,
                                   hy, cyo, H, B);
}